// Round 15
// baseline (132.879 us; speedup 1.0000x reference)
//
#include <hip/hip_runtime.h>
#include <cstdint>

// ---------------------------------------------------------------------------
// LoRA MHA: B=4,S=1024,E=1024,H=16,D=64,R=16.  bf16 MFMA, fp32 accum.
// LoRA folded into the weights: W' = W + B@A (scale=1).
// R15: A/B experiment — R14 pipeline (8-wave attn, p3 gemm_o, fused prep)
// with gemm_qkv swapped back to the R12 2-phase 128^2 core (54.5us kernel
// time vs 60.5 for the 8-phase).  Resolves the R12->R13 coupling anomaly
// (did the 256^2 epilogue warm L2 for attn, or was the "rest" delta noise?).
// ---------------------------------------------------------------------------

typedef __attribute__((ext_vector_type(8))) short bf16x8;
typedef __attribute__((ext_vector_type(4))) float f32x4;
typedef __attribute__((ext_vector_type(16))) float f32x16;
typedef __attribute__((ext_vector_type(4))) unsigned short u16x4;
typedef __attribute__((ext_vector_type(4))) unsigned int u32x4;

__device__ __forceinline__ short f2bf(float f) {
  unsigned u = __builtin_bit_cast(unsigned, f);
  u += 0x7FFFu + ((u >> 16) & 1u);          // RNE
  return (short)(u >> 16);
}

typedef __attribute__((address_space(1))) const unsigned int as1_uint;
typedef __attribute__((address_space(3))) unsigned int as3_uint;

__device__ __forceinline__ void gload_lds16(const short* g, const short* l) {
  __builtin_amdgcn_global_load_lds((as1_uint*)g,
      (as3_uint*)(unsigned int)(uintptr_t)l, 16, 0, 0);
}

__device__ __forceinline__ unsigned cvtpk(float lo, float hi) {
  unsigned r;
  asm("v_cvt_pk_bf16_f32 %0, %1, %2" : "=v"(r) : "v"(lo), "v"(hi));
  return r;
}
__device__ __forceinline__ void plswap(unsigned &a, unsigned &b) {
  asm("v_permlane32_swap_b32 %0, %1" : "+v"(a), "+v"(b));
}

__device__ __forceinline__ void build_pfrag(const f32x16 &s, bf16x8 &f0, bf16x8 &f1) {
  unsigned x0 = cvtpk(s[0], s[1]),  x1 = cvtpk(s[2], s[3]);
  unsigned x2 = cvtpk(s[4], s[5]),  x3 = cvtpk(s[6], s[7]);
  plswap(x0, x2); plswap(x1, x3);
  unsigned y0 = cvtpk(s[8], s[9]),  y1 = cvtpk(s[10], s[11]);
  unsigned y2 = cvtpk(s[12], s[13]), y3 = cvtpk(s[14], s[15]);
  plswap(y0, y2); plswap(y1, y3);
  u32x4 a = {x0, x1, x2, x3}, b = {y0, y1, y2, y3};
  f0 = __builtin_bit_cast(bf16x8, a);
  f1 = __builtin_bit_cast(bf16x8, b);
}

// ---------------------------------------------------------------------------
// Kernel 1: fused prep.  Blocks [0,4096): cast x fp32 -> bf16 [4096][1024].
// Blocks [4096,8192): fold LoRA, W'[p] = W_p + B_p@A_p (fp32 -> bf16).
// ---------------------------------------------------------------------------
__global__ void prep_kernel(const float* __restrict__ x, short* __restrict__ xb,
                            const float* __restrict__ wq, const float* __restrict__ wk,
                            const float* __restrict__ wv, const float* __restrict__ wo,
                            const float* __restrict__ bq, const float* __restrict__ bk,
                            const float* __restrict__ bv, const float* __restrict__ bo,
                            const float* __restrict__ aq, const float* __restrict__ ak,
                            const float* __restrict__ av, const float* __restrict__ ao,
                            short* __restrict__ wbo) {
  const int b = blockIdx.x;
  if (b < 4096) {
    const int idx = b * 256 + threadIdx.x;
    f32x4 v = ((const f32x4*)x)[idx];
    u16x4 o;
    o[0] = (unsigned short)f2bf(v[0]);
    o[1] = (unsigned short)f2bf(v[1]);
    o[2] = (unsigned short)f2bf(v[2]);
    o[3] = (unsigned short)f2bf(v[3]);
    ((u16x4*)xb)[idx] = o;
  } else {
    const int bb = b - 4096;
    const int p = bb >> 10;
    const float* W  = (p == 0) ? wq : (p == 1) ? wk : (p == 2) ? wv : wo;
    const float* Bm = (p == 0) ? bq : (p == 1) ? bk : (p == 2) ? bv : bo;
    const float* A  = (p == 0) ? aq : (p == 1) ? ak : (p == 2) ? av : ao;
    const int idx = (bb & 1023) * 256 + threadIdx.x;
    const int n = idx >> 8;
    const int e4 = idx & 255;
    f32x4 acc = ((const f32x4*)(W + (size_t)n * 1024))[e4];
    const float* br = Bm + n * 16;
    #pragma unroll
    for (int r = 0; r < 16; ++r) {
      const f32x4 a4 = ((const f32x4*)(A + (size_t)r * 1024))[e4];
      const float bl = br[r];
      acc[0] += bl * a4[0];
      acc[1] += bl * a4[1];
      acc[2] += bl * a4[2];
      acc[3] += bl * a4[3];
    }
    u16x4 o;
    o[0] = (unsigned short)f2bf(acc[0]);
    o[1] = (unsigned short)f2bf(acc[1]);
    o[2] = (unsigned short)f2bf(acc[2]);
    o[3] = (unsigned short)f2bf(acc[3]);
    *(u16x4*)(wbo + (size_t)p * 1048576 + (size_t)idx * 4) = o;
  }
}

// ---------------------------------------------------------------------------
// GEMM core, double-buffered 2-phase (R12): per K-step issue STAGE(kt+1)
// first, compute kt, one __syncthreads.  LDS 64 KB.
// ---------------------------------------------------------------------------
__device__ __forceinline__ void gemm_core_db(const short* __restrict__ xrow,
                                             const short* __restrict__ wrow,
                                             short (&As)[2][8192], short (&Bs)[2][8192],
                                             f32x4 (&acc)[4][4]) {
  const int tid = threadIdx.x;
  const int wv = tid >> 6, lane = tid & 63;
  const int wr = wv >> 1, wc = wv & 1;
  const int lrow = lane & 15, lk = lane >> 4;
  const int srow = lane >> 3, sphys = lane & 7;

#define STAGE_G(buf, kt)                                                       \
  {                                                                            \
    _Pragma("unroll")                                                          \
    for (int i = 0; i < 4; ++i) {                                              \
      const int ch = i * 4 + wv;                                               \
      const int row = ch * 8 + srow;                                           \
      const int sl = sphys ^ (row & 7);                                        \
      gload_lds16(xrow + (size_t)row * 1024 + (kt) * 64 + sl * 8, As[buf] + ch * 512); \
      gload_lds16(wrow + (size_t)row * 1024 + (kt) * 64 + sl * 8, Bs[buf] + ch * 512); \
    }                                                                          \
  }

  STAGE_G(0, 0);
  __syncthreads();
  int cur = 0;
  for (int kt = 0; kt < 16; ++kt) {
    if (kt < 15) STAGE_G(cur ^ 1, kt + 1);       // prefetch next K-tile first
    #pragma unroll
    for (int kc = 0; kc < 2; ++kc) {
      bf16x8 af[4], bw[4];
      #pragma unroll
      for (int mi = 0; mi < 4; ++mi) {
        const int row = wr * 64 + mi * 16 + lrow;
        const int slot = (kc * 4 + lk) ^ (row & 7);
        af[mi] = *(const bf16x8*)(As[cur] + row * 64 + slot * 8);
      }
      #pragma unroll
      for (int nj = 0; nj < 4; ++nj) {
        const int row = wc * 64 + nj * 16 + lrow;
        const int slot = (kc * 4 + lk) ^ (row & 7);
        bw[nj] = *(const bf16x8*)(Bs[cur] + row * 64 + slot * 8);
      }
      #pragma unroll
      for (int mi = 0; mi < 4; ++mi)
        #pragma unroll
        for (int nj = 0; nj < 4; ++nj)
          acc[mi][nj] = __builtin_amdgcn_mfma_f32_16x16x32_bf16(af[mi], bw[nj], acc[mi][nj], 0, 0, 0);
    }
    __syncthreads();     // waits prefetch (vmcnt) + all reads of cur done
    cur ^= 1;
  }
#undef STAGE_G
}

// ---------------------------------------------------------------------------
// Kernel 2: merged q/k/v projection, N = 3072 (wb = [q;k;v] row-blocks).
// 1-D grid 768; swizzle: xcd = wg&7 owns bcols [3*xcd, 3*xcd+3), brow-major.
// q scaled by log2(e)/8.  q,k -> [bh][s][d]; v -> [bh][d][s].
// ---------------------------------------------------------------------------
__global__ __launch_bounds__(256)
void gemm_qkv(const short* __restrict__ xb, const short* __restrict__ wb,
              const float* __restrict__ biasq, const float* __restrict__ biask,
              const float* __restrict__ biasv,
              short* __restrict__ qbuf, short* __restrict__ kbuf, short* __restrict__ vtb) {
  __shared__ short As[2][8192];
  __shared__ short Bs[2][8192];
  const int wg = blockIdx.x;              // 0..767
  const int xcd = wg & 7, ix = wg >> 3;   // 96 blocks per XCD
  const int bcol = xcd * 3 + ix % 3;      // 3 W-panels per XCD (768 KB in L2)
  const int brow = ix / 3;                // A-panel reused across the 3 bcols
  const int p = bcol >> 3;                // 0..7 q, 8..15 k, 16..23 v

  const f32x4 fz = {0.f, 0.f, 0.f, 0.f};
  f32x4 acc[4][4];
  #pragma unroll
  for (int a = 0; a < 4; ++a)
    #pragma unroll
    for (int b = 0; b < 4; ++b) acc[a][b] = fz;

  gemm_core_db(xb + (size_t)brow * 128 * 1024,
               wb + (size_t)bcol * 128 * 1024, As, Bs, acc);

  const int tid = threadIdx.x;
  const int wv = tid >> 6, lane = tid & 63;
  const int wr = wv >> 1, wc = wv & 1;
  const int lrow = lane & 15, lk = lane >> 4;
  const float* bias = (p == 0) ? biasq : (p == 1) ? biask : biasv;
  const float oscale = (p == 0) ? 0.18033688f : 1.0f;   // log2(e)/8 into q
  const int c0 = (bcol & 7) * 128;        // col offset within the projection
  float bcv[4];
  #pragma unroll
  for (int nj = 0; nj < 4; ++nj)
    bcv[nj] = bias[c0 + wc * 64 + nj * 16 + lrow];

  #pragma unroll
  for (int mi = 0; mi < 4; ++mi) {
    #pragma unroll
    for (int r = 0; r < 4; ++r) {
      const int gr = brow * 128 + wr * 64 + mi * 16 + lk * 4 + r;   // C/D row
      const int bb = gr >> 10, s = gr & 1023;
      #pragma unroll
      for (int nj = 0; nj < 4; ++nj) {
        const int gc = c0 + wc * 64 + nj * 16 + lrow;               // C/D col
        const float v = (acc[mi][nj][r] + bcv[nj]) * oscale;
        const int h = gc >> 6, d = gc & 63;
        const int bh = bb * 16 + h;
        if (p == 2)
          vtb[((size_t)bh * 64 + d) * 1024 + s] = f2bf(v);
        else
          ((p == 0) ? qbuf : kbuf)[((size_t)bh * 1024 + s) * 64 + d] = f2bf(v);
      }
    }
  }
}

// ---------------------------------------------------------------------------
// Kernel 3: flash attention, swapped 32x32 MFMA form (unchanged from R14).
// 8-wave blocks (512 thr, 256 q-rows), grid (64 bh, 4 qt) = 256 blocks.
// ---------------------------------------------------------------------------
__global__ __launch_bounds__(512)
void attn_kernel(const short* __restrict__ qbuf, const short* __restrict__ kbuf,
                 const short* __restrict__ vtb, short* __restrict__ cb) {
  __shared__ short Ks[2][64 * 64];
  __shared__ short Vs[2][64 * 64];
  const int bh = blockIdx.x, qt = blockIdx.y;
  const int tid = threadIdx.x, w = tid >> 6, lane = tid & 63;
  const int l31 = lane & 31, hi = lane >> 5;
  const int srow = lane >> 3, sphys = lane & 7;
  const short* Qp = qbuf + (size_t)bh * 65536;
  const short* Kp = kbuf + (size_t)bh * 65536;
  const short* Vp = vtb + (size_t)bh * 65536;
  const int q0 = qt * 256 + w * 32;

  bf16x8 bq[4];
  #pragma unroll
  for (int kc = 0; kc < 4; ++kc)
    bq[kc] = *(const bf16x8*)(Qp + (size_t)(q0 + l31) * 64 + kc * 16 + hi * 8);

  const f32x16 fz16 = {0.f,0.f,0.f,0.f,0.f,0.f,0.f,0.f,0.f,0.f,0.f,0.f,0.f,0.f,0.f,0.f};
  float m_run = -1e30f, l_run = 0.f;
  f32x16 acc0 = fz16, acc1 = fz16;

  #define STAGE_KV(buf, tt)                                                  \
    {                                                                        \
      const int t0s = (tt) * 64;                                             \
      const int row = w * 8 + srow;                                          \
      const int sl = sphys ^ (row & 7);                                      \
      gload_lds16(Kp + (size_t)(t0s + row) * 64 + sl * 8, Ks[buf] + w * 512); \
      gload_lds16(Vp + (size_t)row * 1024 + t0s + sl * 8, Vs[buf] + w * 512); \
    }

  STAGE_KV(0, 0);
  __syncthreads();

  int cur = 0;
  for (int tt = 0; tt < 16; ++tt) {
    if (tt < 15) STAGE_KV(cur ^ 1, tt + 1);

    // ---- S^T = K · Q^T ----
    f32x16 s0 = fz16, s1 = fz16;
    __builtin_amdgcn_s_setprio(1);
    #pragma unroll
    for (int kc = 0; kc < 4; ++kc) {
      const int slot = (kc * 2 + hi) ^ (l31 & 7);
      const bf16x8 ak0 = *(const bf16x8*)(Ks[cur] + l31 * 64 + slot * 8);
      const bf16x8 ak1 = *(const bf16x8*)(Ks[cur] + (32 + l31) * 64 + slot * 8);
      s0 = __builtin_amdgcn_mfma_f32_32x32x16_bf16(ak0, bq[kc], s0, 0, 0, 0);
      s1 = __builtin_amdgcn_mfma_f32_32x32x16_bf16(ak1, bq[kc], s1, 0, 0, 0);
    }
    __builtin_amdgcn_s_setprio(0);

    // ---- max: pairwise tree ----
    float t16[16];
    #pragma unroll
    for (int r = 0; r < 8; ++r) t16[r] = fmaxf(s0[2 * r], s0[2 * r + 1]);
    #pragma unroll
    for (int r = 0; r < 8; ++r) t16[8 + r] = fmaxf(s1[2 * r], s1[2 * r + 1]);
    #pragma unroll
    for (int r = 0; r < 8; ++r) t16[r] = fmaxf(t16[r], t16[r + 8]);
    #pragma unroll
    for (int r = 0; r < 4; ++r) t16[r] = fmaxf(t16[r], t16[r + 4]);
    float tm = fmaxf(fmaxf(t16[0], t16[1]), fmaxf(t16[2], t16[3]));
    tm = fmaxf(tm, __shfl_xor(tm, 32, 64));

    // ---- defer-max (T13) ----
    if (__any(tm - m_run > 8.0f)) {
      const float mn = fmaxf(m_run, tm);
      const float alpha = exp2f(m_run - mn);
      m_run = mn;
      l_run *= alpha;
      #pragma unroll
      for (int r = 0; r < 16; ++r) { acc0[r] *= alpha; acc1[r] *= alpha; }
    }

    // ---- P = 2^(S - m), sum via pairwise tree ----
    float a16[16];
    #pragma unroll
    for (int r = 0; r < 16; ++r) { s0[r] = exp2f(s0[r] - m_run); }
    #pragma unroll
    for (int r = 0; r < 16; ++r) { s1[r] = exp2f(s1[r] - m_run); }
    #pragma unroll
    for (int r = 0; r < 8; ++r) a16[r] = s0[2 * r] + s0[2 * r + 1];
    #pragma unroll
    for (int r = 0; r < 8; ++r) a16[8 + r] = s1[2 * r] + s1[2 * r + 1];
    #pragma unroll
    for (int r = 0; r < 8; ++r) a16[r] += a16[r + 8];
    #pragma unroll
    for (int r = 0; r < 4; ++r) a16[r] += a16[r + 4];
    float rs = (a16[0] + a16[1]) + (a16[2] + a16[3]);
    rs += __shfl_xor(rs, 32, 64);
    l_run += rs;

    // ---- P^T fragments (in-register, T12) ----
    bf16x8 pf[4];
    build_pfrag(s0, pf[0], pf[1]);
    build_pfrag(s1, pf[2], pf[3]);

    // ---- O^T += V^T · P^T ----
    __builtin_amdgcn_s_setprio(1);
    #pragma unroll
    for (int kc4 = 0; kc4 < 4; ++kc4) {
      const int slot = (kc4 * 2 + hi) ^ (l31 & 7);
      const bf16x8 av0 = *(const bf16x8*)(Vs[cur] + l31 * 64 + slot * 8);
      const bf16x8 av1 = *(const bf16x8*)(Vs[cur] + (32 + l31) * 64 + slot * 8);
      acc0 = __builtin_amdgcn_mfma_f32_32x32x16_bf16(av0, pf[kc4], acc0, 0, 0, 0);
      acc1 = __builtin_amdgcn_mfma_f32_32x32x16_bf16(av1, pf[kc4], acc1, 0, 0, 0);
    }
    __builtin_amdgcn_s_setprio(0);

    __syncthreads();
    cur ^= 1;
  }

  const int bb = bh >> 4, h = bh & 15;
  const int s = q0 + l31;
  short* crow = cb + (size_t)(bb * 1024 + s) * 1024 + h * 64;
  const float inv = 1.f / l_run;
  #pragma unroll
  for (int rp = 0; rp < 8; ++rp) {
    const int r = rp * 2;
    const int d = (r & 3) + 8 * (r >> 2) + 4 * hi;
    const unsigned p0 = (unsigned)(unsigned short)f2bf(acc0[r] * inv)
                      | ((unsigned)(unsigned short)f2bf(acc0[r + 1] * inv) << 16);
    const unsigned p1 = (unsigned)(unsigned short)f2bf(acc1[r] * inv)
                      | ((unsigned)(unsigned short)f2bf(acc1[r + 1] * inv) << 16);
    *(unsigned*)(crow + d) = p0;
    *(unsigned*)(crow + 32 + d) = p1;
  }
  #undef STAGE_KV
}

// ---------------------------------------------------------------------------
// GEMM core, depth-2 counted-vmcnt pipeline (gemm_o; unchanged).
// ---------------------------------------------------------------------------
__device__ __forceinline__ void gemm_core_p3(const short* __restrict__ xrow,
                                             const short* __restrict__ wrow,
                                             short (&As)[3][8192], short (&Bs)[3][8192],
                                             f32x4 (&acc)[4][4]) {
  const int tid = threadIdx.x;
  const int wv = tid >> 6, lane = tid & 63;
  const int wr = wv >> 1, wc = wv & 1;
  const int lrow = lane & 15, lk = lane >> 4;
  const int srow = lane >> 3, sphys = lane & 7;

#define STAGE_G(buf, kt)                                                       \
  {                                                                            \
    _Pragma("unroll")                                                          \
    for (int i = 0; i < 4; ++i) {                                              \
      const int ch = i * 4 + wv;                                               \
      const int row = ch * 8 + srow;                                           \
      const int sl = sphys ^ (row & 7);                                        \
      gload_lds16(xrow + (size_t)row * 1024 + (kt) * 64 + sl * 8, As[buf] + ch * 512); \
      gload_lds16(wrow + (size_t)row * 1024 + (kt) * 64 + sl * 8, Bs[buf] + ch * 512); \
    }                                                                          \
  }

  STAGE_G(0, 0);
  STAGE_G(1, 1);
  int cur = 0;
  for (int kt = 0; kt < 16; ++kt) {
    if (kt < 14) {
      const int nb = (cur == 0) ? 2 : (cur - 1);   // (kt+2)%3
      STAGE_G(nb, kt + 2);
      asm volatile("s_waitcnt vmcnt(16)" ::: "memory");
    } else if (kt == 14) {
      asm volatile("s_waitcnt vmcnt(8)" ::: "memory");
    } else {
      asm volatile("s_waitcnt vmcnt(0)" ::: "memory");
    }
    __builtin_amdgcn_s_barrier();

    #pragma unroll
    for (int kc = 0; kc < 2; ++kc) {
      bf16x8 af[4], bw[4];
      #pragma unroll
      for (int mi = 0; mi < 4; ++mi) {
        const int row = wr * 64 + mi * 16 + lrow;
        const int slot = (kc * 4 + lk) ^ (row & 7);
        af[mi] = *(const bf16x8*)(As[cur] + row * 64 + slot * 8);
      }
      #pragma unroll
      for (int nj = 0; nj < 4; ++nj) {
        const int row = wc * 64 + nj * 16 + lrow;
        const int slot = (kc * 4 + lk) ^ (row & 7);
        bw[nj] = *(const bf16x8*)(Bs[cur] + row * 64 + slot * 8);
      }
      __builtin_amdgcn_s_setprio(1);
      #pragma unroll
      for (int mi = 0; mi < 4; ++mi)
        #pragma unroll
        for (int nj = 0; nj < 4; ++nj)
          acc[mi][nj] = __builtin_amdgcn_mfma_f32_16x16x32_bf16(af[mi], bw[nj], acc[mi][nj], 0, 0, 0);
      __builtin_amdgcn_s_setprio(0);
    }

    asm volatile("s_waitcnt lgkmcnt(0)" ::: "memory");
    __builtin_amdgcn_s_barrier();
    cur = (cur == 2) ? 0 : (cur + 1);
  }
#undef STAGE_G
}

// ---------------------------------------------------------------------------
// Kernel 4: o-projection -> fp32 d_out (p3 core, grid 256 = 1/CU).
// ---------------------------------------------------------------------------
__global__ __launch_bounds__(256)
void gemm_o(const short* __restrict__ cb, const short* __restrict__ wo,
            const float* __restrict__ biaso, float* __restrict__ out) {
  __shared__ short As[3][8192];
  __shared__ short Bs[3][8192];
  const int brow = blockIdx.y, bcol = blockIdx.x;
  const f32x4 fz = {0.f, 0.f, 0.f, 0.f};
  f32x4 acc[4][4];
  #pragma unroll
  for (int a = 0; a < 4; ++a)
    #pragma unroll
    for (int b = 0; b < 4; ++b) acc[a][b] = fz;

  gemm_core_p3(cb + (size_t)brow * 128 * 1024, wo + (size_t)bcol * 128 * 1024,
               As, Bs, acc);

  const int tid = threadIdx.x;
  const int wv = tid >> 6, lane = tid & 63;
  const int wr = wv >> 1, wc = wv & 1;
  const int lrow = lane & 15, lk = lane >> 4;
  float bcv[4];
  #pragma unroll
  for (int nj = 0; nj < 4; ++nj)
    bcv[nj] = biaso[bcol * 128 + wc * 64 + nj * 16 + lrow];

  #pragma unroll
  for (int mi = 0; mi < 4; ++mi) {
    #pragma unroll
    for (int r = 0; r < 4; ++r) {
      const int gr = brow * 128 + wr * 64 + mi * 16 + lk * 4 + r;
      #pragma unroll
      for (int nj = 0; nj < 4; ++nj) {
        const int gc = bcol * 128 + wc * 64 + nj * 16 + lrow;
        out[(size_t)gr * 1024 + gc] = acc[mi][nj][r] + bcv[nj];
      }
    }
  }
}

// ---------------------------------------------------------------------------
extern "C" void kernel_launch(void* const* d_in, const int* in_sizes, int n_in,
                              void* d_out, int out_size, void* d_ws, size_t ws_size,
                              hipStream_t stream) {
  (void)in_sizes; (void)n_in; (void)out_size; (void)ws_size;
  const float* x   = (const float*)d_in[0];
  const float* qw  = (const float*)d_in[1];
  const float* qb  = (const float*)d_in[2];
  const float* qla = (const float*)d_in[3];
  const float* qlb = (const float*)d_in[4];
  const float* kw  = (const float*)d_in[5];
  const float* kb  = (const float*)d_in[6];
  const float* kla = (const float*)d_in[7];
  const float* klb = (const float*)d_in[8];
  const float* vw  = (const float*)d_in[9];
  const float* vb  = (const float*)d_in[10];
  const float* vla = (const float*)d_in[11];
  const float* vlb = (const float*)d_in[12];
  const float* ow  = (const float*)d_in[13];
  const float* ob  = (const float*)d_in[14];
  const float* ola = (const float*)d_in[15];
  const float* olb = (const float*)d_in[16];

  short* xb   = (short*)d_ws;                         // 4096*1024 bf16 (reused as ctx)
  short* wb   = xb + (size_t)4096 * 1024;             // 4*1024*1024 bf16
  short* qbuf = wb + (size_t)4 * 1024 * 1024;         // 64*1024*64 each
  short* kbuf = qbuf + (size_t)4194304;
  short* vtb  = kbuf + (size_t)4194304;               // total 40 MB

  prep_kernel<<<8192, 256, 0, stream>>>(x, xb, qw, kw, vw, ow,
                                        qlb, klb, vlb, olb,
                                        qla, kla, vla, ola, wb);
  gemm_qkv<<<768, 256, 0, stream>>>(xb, wb, qb, kb, vb, qbuf, kbuf, vtb);
  attn_kernel<<<dim3(64, 4), 512, 0, stream>>>(qbuf, kbuf, vtb, xb);
  gemm_o<<<dim3(8, 32), 256, 0, stream>>>(xb, wb + (size_t)3 * 1024 * 1024, ob, (float*)d_out);
}

// Round 16
// 129.270 us; speedup vs baseline: 1.0279x; 1.0279x over previous
//
#include <hip/hip_runtime.h>
#include <cstdint>

// ---------------------------------------------------------------------------
// LoRA MHA: B=4,S=1024,E=1024,H=16,D=64,R=16.  bf16 MFMA, fp32 accum.
// LoRA folded into the weights: W' = W + B@A (scale=1).
// R16: revert to R14 exactly (measured best, 129.84us).  R15's A/B proved
// the 8-phase 256^2 qkv + rest-of-pipeline coupling is real (L2 warmth for
// attn outweighs qkv's own +6us kernel time).
// ---------------------------------------------------------------------------

typedef __attribute__((ext_vector_type(8))) short bf16x8;
typedef __attribute__((ext_vector_type(4))) float f32x4;
typedef __attribute__((ext_vector_type(16))) float f32x16;
typedef __attribute__((ext_vector_type(4))) unsigned short u16x4;
typedef __attribute__((ext_vector_type(4))) unsigned int u32x4;

__device__ __forceinline__ short f2bf(float f) {
  unsigned u = __builtin_bit_cast(unsigned, f);
  u += 0x7FFFu + ((u >> 16) & 1u);          // RNE
  return (short)(u >> 16);
}

typedef __attribute__((address_space(1))) const unsigned int as1_uint;
typedef __attribute__((address_space(3))) unsigned int as3_uint;

__device__ __forceinline__ void gload_lds16(const short* g, const short* l) {
  __builtin_amdgcn_global_load_lds((as1_uint*)g,
      (as3_uint*)(unsigned int)(uintptr_t)l, 16, 0, 0);
}

__device__ __forceinline__ unsigned cvtpk(float lo, float hi) {
  unsigned r;
  asm("v_cvt_pk_bf16_f32 %0, %1, %2" : "=v"(r) : "v"(lo), "v"(hi));
  return r;
}
__device__ __forceinline__ void plswap(unsigned &a, unsigned &b) {
  asm("v_permlane32_swap_b32 %0, %1" : "+v"(a), "+v"(b));
}

__device__ __forceinline__ void build_pfrag(const f32x16 &s, bf16x8 &f0, bf16x8 &f1) {
  unsigned x0 = cvtpk(s[0], s[1]),  x1 = cvtpk(s[2], s[3]);
  unsigned x2 = cvtpk(s[4], s[5]),  x3 = cvtpk(s[6], s[7]);
  plswap(x0, x2); plswap(x1, x3);
  unsigned y0 = cvtpk(s[8], s[9]),  y1 = cvtpk(s[10], s[11]);
  unsigned y2 = cvtpk(s[12], s[13]), y3 = cvtpk(s[14], s[15]);
  plswap(y0, y2); plswap(y1, y3);
  u32x4 a = {x0, x1, x2, x3}, b = {y0, y1, y2, y3};
  f0 = __builtin_bit_cast(bf16x8, a);
  f1 = __builtin_bit_cast(bf16x8, b);
}

// ---------------------------------------------------------------------------
// Kernel 1: fused prep.  Blocks [0,4096): cast x fp32 -> bf16 [4096][1024].
// Blocks [4096,8192): fold LoRA, W'[p] = W_p + B_p@A_p (fp32 -> bf16).
// ---------------------------------------------------------------------------
__global__ void prep_kernel(const float* __restrict__ x, short* __restrict__ xb,
                            const float* __restrict__ wq, const float* __restrict__ wk,
                            const float* __restrict__ wv, const float* __restrict__ wo,
                            const float* __restrict__ bq, const float* __restrict__ bk,
                            const float* __restrict__ bv, const float* __restrict__ bo,
                            const float* __restrict__ aq, const float* __restrict__ ak,
                            const float* __restrict__ av, const float* __restrict__ ao,
                            short* __restrict__ wbo) {
  const int b = blockIdx.x;
  if (b < 4096) {
    const int idx = b * 256 + threadIdx.x;
    f32x4 v = ((const f32x4*)x)[idx];
    u16x4 o;
    o[0] = (unsigned short)f2bf(v[0]);
    o[1] = (unsigned short)f2bf(v[1]);
    o[2] = (unsigned short)f2bf(v[2]);
    o[3] = (unsigned short)f2bf(v[3]);
    ((u16x4*)xb)[idx] = o;
  } else {
    const int bb = b - 4096;
    const int p = bb >> 10;
    const float* W  = (p == 0) ? wq : (p == 1) ? wk : (p == 2) ? wv : wo;
    const float* Bm = (p == 0) ? bq : (p == 1) ? bk : (p == 2) ? bv : bo;
    const float* A  = (p == 0) ? aq : (p == 1) ? ak : (p == 2) ? av : ao;
    const int idx = (bb & 1023) * 256 + threadIdx.x;
    const int n = idx >> 8;
    const int e4 = idx & 255;
    f32x4 acc = ((const f32x4*)(W + (size_t)n * 1024))[e4];
    const float* br = Bm + n * 16;
    #pragma unroll
    for (int r = 0; r < 16; ++r) {
      const f32x4 a4 = ((const f32x4*)(A + (size_t)r * 1024))[e4];
      const float bl = br[r];
      acc[0] += bl * a4[0];
      acc[1] += bl * a4[1];
      acc[2] += bl * a4[2];
      acc[3] += bl * a4[3];
    }
    u16x4 o;
    o[0] = (unsigned short)f2bf(acc[0]);
    o[1] = (unsigned short)f2bf(acc[1]);
    o[2] = (unsigned short)f2bf(acc[2]);
    o[3] = (unsigned short)f2bf(acc[3]);
    *(u16x4*)(wbo + (size_t)p * 1048576 + (size_t)idx * 4) = o;
  }
}

// ---------------------------------------------------------------------------
// Kernel 2: merged q/k/v projection, 256x256 tile, 8 waves (2M x 4N),
// 8-phase counted-vmcnt schedule.  Grid 192 = 16 brow x 12 bcol, XCD
// transpose swizzle.  LDS 128 KB = 2buf x 2half x 128x64 x (A,B).
// ---------------------------------------------------------------------------
__global__ __launch_bounds__(512, 2)
void gemm_qkv(const short* __restrict__ xb, const short* __restrict__ wb,
              const float* __restrict__ biasq, const float* __restrict__ biask,
              const float* __restrict__ biasv,
              short* __restrict__ qbuf, short* __restrict__ kbuf, short* __restrict__ vtb) {
  __shared__ short Ah[2][2][8192];     // [buf][half][128 rows * 64 cols]
  __shared__ short Bh[2][2][8192];
  const int wg = blockIdx.x;                    // 0..191
  const int swz = (wg & 7) * 24 + (wg >> 3);    // XCD owns 2 brows x 12 bcols
  const int brow = swz / 12, bcol = swz % 12;
  const int tid = threadIdx.x;
  const int wid = tid >> 6, lane = tid & 63;
  const int wr = wid >> 2, wc = wid & 3;        // 2M x 4N wave grid
  const int lrow = lane & 15, lk = lane >> 4;
  const int sl8 = (tid & 7) ^ ((tid >> 3) & 7); // inverse-swizzled source slot

  const short* Asrc = xb + (size_t)brow * 256 * 1024;
  const short* Bsrc = wb + (size_t)bcol * 256 * 1024;

#define STAGE_H(SRC, LDS, hf, kt, buf)                                         \
  { _Pragma("unroll")                                                          \
    for (int i = 0; i < 2; ++i) {                                              \
      const int row = (hf) * 128 + i * 64 + (tid >> 3);                        \
      gload_lds16(SRC + (size_t)row * 1024 + (kt) * 64 + sl8 * 8,              \
                  LDS[buf][hf] + (i * 64 + wid * 8) * 64);                     \
    } }

  const f32x4 fz = {0.f, 0.f, 0.f, 0.f};
  f32x4 acc[8][4];
  #pragma unroll
  for (int a = 0; a < 8; ++a)
    #pragma unroll
    for (int b = 0; b < 4; ++b) acc[a][b] = fz;

  STAGE_H(Asrc, Ah, 0, 0, 0)
  STAGE_H(Asrc, Ah, 1, 0, 0)
  STAGE_H(Bsrc, Bh, 0, 0, 0)
  STAGE_H(Bsrc, Bh, 1, 0, 0)
  STAGE_H(Bsrc, Bh, 0, 1, 1)
  STAGE_H(Bsrc, Bh, 1, 1, 1)
  asm volatile("s_waitcnt vmcnt(4)" ::: "memory");
  __builtin_amdgcn_s_barrier();

  const int bhalf = wc >> 1;
  for (int t = 0; t < 16; ++t) {
    const int cur = t & 1;
    bf16x8 bfr[4][2];
    #pragma unroll
    for (int q = 0; q < 4; ++q) {
      if (q == 0) {
        #pragma unroll
        for (int nj = 0; nj < 4; ++nj) {
          const int rr = (wc & 1) * 64 + nj * 16 + lrow;
          #pragma unroll
          for (int kc = 0; kc < 2; ++kc)
            bfr[nj][kc] = *(const bf16x8*)(&Bh[cur][bhalf][rr * 64 + (((kc * 4 + lk) ^ (rr & 7)) * 8)]);
        }
      }
      bf16x8 afr[2][2];
      #pragma unroll
      for (int m2 = 0; m2 < 2; ++m2) {
        const int rr = q * 32 + m2 * 16 + lrow;
        #pragma unroll
        for (int kc = 0; kc < 2; ++kc)
          afr[m2][kc] = *(const bf16x8*)(&Ah[cur][wr][rr * 64 + (((kc * 4 + lk) ^ (rr & 7)) * 8)]);
      }
      if (q == 0) { if (t + 1 < 16) STAGE_H(Asrc, Ah, 0, t + 1, cur ^ 1) }
      else if (q == 1) { if (t + 1 < 16) STAGE_H(Asrc, Ah, 1, t + 1, cur ^ 1) }
      else if (q == 2) { if (t + 2 < 16) STAGE_H(Bsrc, Bh, 0, t + 2, cur) }
      else             { if (t + 2 < 16) STAGE_H(Bsrc, Bh, 1, t + 2, cur) }

      if (q == 0) asm volatile("s_waitcnt lgkmcnt(8)" ::: "memory");
      __builtin_amdgcn_s_barrier();
      asm volatile("s_waitcnt lgkmcnt(0)" ::: "memory");
      __builtin_amdgcn_s_setprio(1);
      #pragma unroll
      for (int kc = 0; kc < 2; ++kc)
        #pragma unroll
        for (int m2 = 0; m2 < 2; ++m2)
          #pragma unroll
          for (int nj = 0; nj < 4; ++nj)
            acc[q * 2 + m2][nj] = __builtin_amdgcn_mfma_f32_16x16x32_bf16(
                afr[m2][kc], bfr[nj][kc], acc[q * 2 + m2][nj], 0, 0, 0);
      __builtin_amdgcn_s_setprio(0);
      if (q == 3) {
        if (t < 14) asm volatile("s_waitcnt vmcnt(4)" ::: "memory");
        else        asm volatile("s_waitcnt vmcnt(0)" ::: "memory");
      }
      __builtin_amdgcn_s_barrier();
    }
  }
#undef STAGE_H

  const int p = bcol >> 2;
  const float* bias = (p == 0) ? biasq : (p == 1) ? biask : biasv;
  const float oscale = (p == 0) ? 0.18033688f : 1.0f;
  const int c0 = (bcol & 3) * 256 + wc * 64;
  float bcv[4];
  #pragma unroll
  for (int nj = 0; nj < 4; ++nj)
    bcv[nj] = bias[c0 + nj * 16 + lrow];

  #pragma unroll
  for (int mi = 0; mi < 8; ++mi) {
    #pragma unroll
    for (int r = 0; r < 4; ++r) {
      const int gr = brow * 256 + wr * 128 + mi * 16 + lk * 4 + r;   // C/D row
      const int bb = gr >> 10, s = gr & 1023;
      #pragma unroll
      for (int nj = 0; nj < 4; ++nj) {
        const int gc = c0 + nj * 16 + lrow;                          // 0..1023
        const float v = (acc[mi][nj][r] + bcv[nj]) * oscale;
        const int h = gc >> 6, d = gc & 63;
        const int bh = bb * 16 + h;
        if (p == 2)
          vtb[((size_t)bh * 64 + d) * 1024 + s] = f2bf(v);
        else
          ((p == 0) ? qbuf : kbuf)[((size_t)bh * 1024 + s) * 64 + d] = f2bf(v);
      }
    }
  }
}

// ---------------------------------------------------------------------------
// Kernel 3: flash attention, swapped 32x32 MFMA form.
// 8-wave blocks (512 thr, 256 q-rows), grid (64 bh, 4 qt) = 256 blocks
// (1/CU).  K/V staged once per block per tile (chunk = wave id).
// ---------------------------------------------------------------------------
__global__ __launch_bounds__(512)
void attn_kernel(const short* __restrict__ qbuf, const short* __restrict__ kbuf,
                 const short* __restrict__ vtb, short* __restrict__ cb) {
  __shared__ short Ks[2][64 * 64];
  __shared__ short Vs[2][64 * 64];
  const int bh = blockIdx.x, qt = blockIdx.y;
  const int tid = threadIdx.x, w = tid >> 6, lane = tid & 63;
  const int l31 = lane & 31, hi = lane >> 5;
  const int srow = lane >> 3, sphys = lane & 7;
  const short* Qp = qbuf + (size_t)bh * 65536;
  const short* Kp = kbuf + (size_t)bh * 65536;
  const short* Vp = vtb + (size_t)bh * 65536;
  const int q0 = qt * 256 + w * 32;

  bf16x8 bq[4];
  #pragma unroll
  for (int kc = 0; kc < 4; ++kc)
    bq[kc] = *(const bf16x8*)(Qp + (size_t)(q0 + l31) * 64 + kc * 16 + hi * 8);

  const f32x16 fz16 = {0.f,0.f,0.f,0.f,0.f,0.f,0.f,0.f,0.f,0.f,0.f,0.f,0.f,0.f,0.f,0.f};
  float m_run = -1e30f, l_run = 0.f;
  f32x16 acc0 = fz16, acc1 = fz16;

  // stage: 8 chunks of 8 rows, one chunk per wave, per matrix
  #define STAGE_KV(buf, tt)                                                  \
    {                                                                        \
      const int t0s = (tt) * 64;                                             \
      const int row = w * 8 + srow;                                          \
      const int sl = sphys ^ (row & 7);                                      \
      gload_lds16(Kp + (size_t)(t0s + row) * 64 + sl * 8, Ks[buf] + w * 512); \
      gload_lds16(Vp + (size_t)row * 1024 + t0s + sl * 8, Vs[buf] + w * 512); \
    }

  STAGE_KV(0, 0);
  __syncthreads();

  int cur = 0;
  for (int tt = 0; tt < 16; ++tt) {
    if (tt < 15) STAGE_KV(cur ^ 1, tt + 1);

    // ---- S^T = K · Q^T ----
    f32x16 s0 = fz16, s1 = fz16;
    __builtin_amdgcn_s_setprio(1);
    #pragma unroll
    for (int kc = 0; kc < 4; ++kc) {
      const int slot = (kc * 2 + hi) ^ (l31 & 7);
      const bf16x8 ak0 = *(const bf16x8*)(Ks[cur] + l31 * 64 + slot * 8);
      const bf16x8 ak1 = *(const bf16x8*)(Ks[cur] + (32 + l31) * 64 + slot * 8);
      s0 = __builtin_amdgcn_mfma_f32_32x32x16_bf16(ak0, bq[kc], s0, 0, 0, 0);
      s1 = __builtin_amdgcn_mfma_f32_32x32x16_bf16(ak1, bq[kc], s1, 0, 0, 0);
    }
    __builtin_amdgcn_s_setprio(0);

    // ---- max: pairwise tree ----
    float t16[16];
    #pragma unroll
    for (int r = 0; r < 8; ++r) t16[r] = fmaxf(s0[2 * r], s0[2 * r + 1]);
    #pragma unroll
    for (int r = 0; r < 8; ++r) t16[8 + r] = fmaxf(s1[2 * r], s1[2 * r + 1]);
    #pragma unroll
    for (int r = 0; r < 8; ++r) t16[r] = fmaxf(t16[r], t16[r + 8]);
    #pragma unroll
    for (int r = 0; r < 4; ++r) t16[r] = fmaxf(t16[r], t16[r + 4]);
    float tm = fmaxf(fmaxf(t16[0], t16[1]), fmaxf(t16[2], t16[3]));
    tm = fmaxf(tm, __shfl_xor(tm, 32, 64));

    // ---- defer-max (T13) ----
    if (__any(tm - m_run > 8.0f)) {
      const float mn = fmaxf(m_run, tm);
      const float alpha = exp2f(m_run - mn);
      m_run = mn;
      l_run *= alpha;
      #pragma unroll
      for (int r = 0; r < 16; ++r) { acc0[r] *= alpha; acc1[r] *= alpha; }
    }

    // ---- P = 2^(S - m), sum via pairwise tree ----
    float a16[16];
    #pragma unroll
    for (int r = 0; r < 16; ++r) { s0[r] = exp2f(s0[r] - m_run); }
    #pragma unroll
    for (int r = 0; r < 16; ++r) { s1[r] = exp2f(s1[r] - m_run); }
    #pragma unroll
    for (int r = 0; r < 8; ++r) a16[r] = s0[2 * r] + s0[2 * r + 1];
    #pragma unroll
    for (int r = 0; r < 8; ++r) a16[8 + r] = s1[2 * r] + s1[2 * r + 1];
    #pragma unroll
    for (int r = 0; r < 8; ++r) a16[r] += a16[r + 8];
    #pragma unroll
    for (int r = 0; r < 4; ++r) a16[r] += a16[r + 4];
    float rs = (a16[0] + a16[1]) + (a16[2] + a16[3]);
    rs += __shfl_xor(rs, 32, 64);
    l_run += rs;

    // ---- P^T fragments (in-register, T12) ----
    bf16x8 pf[4];
    build_pfrag(s0, pf[0], pf[1]);
    build_pfrag(s1, pf[2], pf[3]);

    // ---- O^T += V^T · P^T ----
    __builtin_amdgcn_s_setprio(1);
    #pragma unroll
    for (int kc4 = 0; kc4 < 4; ++kc4) {
      const int slot = (kc4 * 2 + hi) ^ (l31 & 7);
      const bf16x8 av0 = *(const bf16x8*)(Vs[cur] + l31 * 64 + slot * 8);
      const bf16x8 av1 = *(const bf16x8*)(Vs[cur] + (32 + l31) * 64 + slot * 8);
      acc0 = __builtin_amdgcn_mfma_f32_32x32x16_bf16(av0, pf[kc4], acc0, 0, 0, 0);
      acc1 = __builtin_amdgcn_mfma_f32_32x32x16_bf16(av1, pf[kc4], acc1, 0, 0, 0);
    }
    __builtin_amdgcn_s_setprio(0);

    __syncthreads();
    cur ^= 1;
  }

  const int bb = bh >> 4, h = bh & 15;
  const int s = q0 + l31;
  short* crow = cb + (size_t)(bb * 1024 + s) * 1024 + h * 64;
  const float inv = 1.f / l_run;
  #pragma unroll
  for (int rp = 0; rp < 8; ++rp) {
    const int r = rp * 2;
    const int d = (r & 3) + 8 * (r >> 2) + 4 * hi;
    const unsigned p0 = (unsigned)(unsigned short)f2bf(acc0[r] * inv)
                      | ((unsigned)(unsigned short)f2bf(acc0[r + 1] * inv) << 16);
    const unsigned p1 = (unsigned)(unsigned short)f2bf(acc1[r] * inv)
                      | ((unsigned)(unsigned short)f2bf(acc1[r + 1] * inv) << 16);
    *(unsigned*)(crow + d) = p0;
    *(unsigned*)(crow + 32 + d) = p1;
  }
  #undef STAGE_KV
}

// ---------------------------------------------------------------------------
// GEMM core, depth-2 counted-vmcnt pipeline (gemm_o).
// ---------------------------------------------------------------------------
__device__ __forceinline__ void gemm_core_p3(const short* __restrict__ xrow,
                                             const short* __restrict__ wrow,
                                             short (&As)[3][8192], short (&Bs)[3][8192],
                                             f32x4 (&acc)[4][4]) {
  const int tid = threadIdx.x;
  const int wv = tid >> 6, lane = tid & 63;
  const int wr = wv >> 1, wc = wv & 1;
  const int lrow = lane & 15, lk = lane >> 4;
  const int srow = lane >> 3, sphys = lane & 7;

#define STAGE_G(buf, kt)                                                       \
  {                                                                            \
    _Pragma("unroll")                                                          \
    for (int i = 0; i < 4; ++i) {                                              \
      const int ch = i * 4 + wv;                                               \
      const int row = ch * 8 + srow;                                           \
      const int sl = sphys ^ (row & 7);                                        \
      gload_lds16(xrow + (size_t)row * 1024 + (kt) * 64 + sl * 8, As[buf] + ch * 512); \
      gload_lds16(wrow + (size_t)row * 1024 + (kt) * 64 + sl * 8, Bs[buf] + ch * 512); \
    }                                                                          \
  }

  STAGE_G(0, 0);
  STAGE_G(1, 1);
  int cur = 0;
  for (int kt = 0; kt < 16; ++kt) {
    if (kt < 14) {
      const int nb = (cur == 0) ? 2 : (cur - 1);   // (kt+2)%3
      STAGE_G(nb, kt + 2);
      asm volatile("s_waitcnt vmcnt(16)" ::: "memory");
    } else if (kt == 14) {
      asm volatile("s_waitcnt vmcnt(8)" ::: "memory");
    } else {
      asm volatile("s_waitcnt vmcnt(0)" ::: "memory");
    }
    __builtin_amdgcn_s_barrier();

    #pragma unroll
    for (int kc = 0; kc < 2; ++kc) {
      bf16x8 af[4], bw[4];
      #pragma unroll
      for (int mi = 0; mi < 4; ++mi) {
        const int row = wr * 64 + mi * 16 + lrow;
        const int slot = (kc * 4 + lk) ^ (row & 7);
        af[mi] = *(const bf16x8*)(As[cur] + row * 64 + slot * 8);
      }
      #pragma unroll
      for (int nj = 0; nj < 4; ++nj) {
        const int row = wc * 64 + nj * 16 + lrow;
        const int slot = (kc * 4 + lk) ^ (row & 7);
        bw[nj] = *(const bf16x8*)(Bs[cur] + row * 64 + slot * 8);
      }
      __builtin_amdgcn_s_setprio(1);
      #pragma unroll
      for (int mi = 0; mi < 4; ++mi)
        #pragma unroll
        for (int nj = 0; nj < 4; ++nj)
          acc[mi][nj] = __builtin_amdgcn_mfma_f32_16x16x32_bf16(af[mi], bw[nj], acc[mi][nj], 0, 0, 0);
      __builtin_amdgcn_s_setprio(0);
    }

    asm volatile("s_waitcnt lgkmcnt(0)" ::: "memory");
    __builtin_amdgcn_s_barrier();
    cur = (cur == 2) ? 0 : (cur + 1);
  }
#undef STAGE_G
}

// ---------------------------------------------------------------------------
// Kernel 4: o-projection -> fp32 d_out (p3 core, grid 256 = 1/CU).
// ---------------------------------------------------------------------------
__global__ __launch_bounds__(256)
void gemm_o(const short* __restrict__ cb, const short* __restrict__ wo,
            const float* __restrict__ biaso, float* __restrict__ out) {
  __shared__ short As[3][8192];
  __shared__ short Bs[3][8192];
  const int brow = blockIdx.y, bcol = blockIdx.x;
  const f32x4 fz = {0.f, 0.f, 0.f, 0.f};
  f32x4 acc[4][4];
  #pragma unroll
  for (int a = 0; a < 4; ++a)
    #pragma unroll
    for (int b = 0; b < 4; ++b) acc[a][b] = fz;

  gemm_core_p3(cb + (size_t)brow * 128 * 1024, wo + (size_t)bcol * 128 * 1024,
               As, Bs, acc);

  const int tid = threadIdx.x;
  const int wv = tid >> 6, lane = tid & 63;
  const int wr = wv >> 1, wc = wv & 1;
  const int lrow = lane & 15, lk = lane >> 4;
  float bcv[4];
  #pragma unroll
  for (int nj = 0; nj < 4; ++nj)
    bcv[nj] = biaso[bcol * 128 + wc * 64 + nj * 16 + lrow];

  #pragma unroll
  for (int mi = 0; mi < 4; ++mi) {
    #pragma unroll
    for (int r = 0; r < 4; ++r) {
      const int gr = brow * 128 + wr * 64 + mi * 16 + lk * 4 + r;
      #pragma unroll
      for (int nj = 0; nj < 4; ++nj) {
        const int gc = bcol * 128 + wc * 64 + nj * 16 + lrow;
        out[(size_t)gr * 1024 + gc] = acc[mi][nj][r] + bcv[nj];
      }
    }
  }
}

// ---------------------------------------------------------------------------
extern "C" void kernel_launch(void* const* d_in, const int* in_sizes, int n_in,
                              void* d_out, int out_size, void* d_ws, size_t ws_size,
                              hipStream_t stream) {
  (void)in_sizes; (void)n_in; (void)out_size; (void)ws_size;
  const float* x   = (const float*)d_in[0];
  const float* qw  = (const float*)d_in[1];
  const float* qb  = (const float*)d_in[2];
  const float* qla = (const float*)d_in[3];
  const float* qlb = (const float*)d_in[4];
  const float* kw  = (const float*)d_in[5];
  const float* kb  = (const float*)d_in[6];
  const float* kla = (const float*)d_in[7];
  const float* klb = (const float*)d_in[8];
  const float* vw  = (const float*)d_in[9];
  const float* vb  = (const float*)d_in[10];
  const float* vla = (const float*)d_in[11];
  const float* vlb = (const float*)d_in[12];
  const float* ow  = (const float*)d_in[13];
  const float* ob  = (const float*)d_in[14];
  const float* ola = (const float*)d_in[15];
  const float* olb = (const float*)d_in[16];

  short* xb   = (short*)d_ws;                         // 4096*1024 bf16 (reused as ctx)
  short* wb   = xb + (size_t)4096 * 1024;             // 4*1024*1024 bf16
  short* qbuf = wb + (size_t)4 * 1024 * 1024;         // 64*1024*64 each
  short* kbuf = qbuf + (size_t)4194304;
  short* vtb  = kbuf + (size_t)4194304;               // total 40 MB

  prep_kernel<<<8192, 256, 0, stream>>>(x, xb, qw, kw, vw, ow,
                                        qlb, klb, vlb, olb,
                                        qla, kla, vla, ola, wb);
  gemm_qkv<<<192, 512, 0, stream>>>(xb, wb, qb, kb, vb, qbuf, kbuf, vtb);
  attn_kernel<<<dim3(64, 4), 512, 0, stream>>>(qbuf, kbuf, vtb, xb);
  gemm_o<<<dim3(8, 32), 256, 0, stream>>>(xb, wb + (size_t)3 * 1024 * 1024, ob, (float*)d_out);
}

// Round 17
// 128.579 us; speedup vs baseline: 1.0334x; 1.0054x over previous
//
#include <hip/hip_runtime.h>
#include <cstdint>

// ---------------------------------------------------------------------------
// LoRA MHA: B=4,S=1024,E=1024,H=16,D=64,R=16.  bf16 MFMA, fp32 accum.
// LoRA folded into the weights: W' = W + B@A (scale=1).
// R17: R16 base + attn staging switched from __syncthreads (vmcnt-0 drain)
// to the proven p3 counted-vmcnt 3-buffer ring (T4): per tile
// {STAGE(tt+1) -> buf (tt+1)%3 ; vmcnt(2) ; lgkmcnt(0) ; raw barrier ;
//  compute buf tt%3}.  Loads keep a standing lead across barriers.
// qkv (8-phase 256^2), gemm_o (p3), prep unchanged.
// ---------------------------------------------------------------------------

typedef __attribute__((ext_vector_type(8))) short bf16x8;
typedef __attribute__((ext_vector_type(4))) float f32x4;
typedef __attribute__((ext_vector_type(16))) float f32x16;
typedef __attribute__((ext_vector_type(4))) unsigned short u16x4;
typedef __attribute__((ext_vector_type(4))) unsigned int u32x4;

__device__ __forceinline__ short f2bf(float f) {
  unsigned u = __builtin_bit_cast(unsigned, f);
  u += 0x7FFFu + ((u >> 16) & 1u);          // RNE
  return (short)(u >> 16);
}

typedef __attribute__((address_space(1))) const unsigned int as1_uint;
typedef __attribute__((address_space(3))) unsigned int as3_uint;

__device__ __forceinline__ void gload_lds16(const short* g, const short* l) {
  __builtin_amdgcn_global_load_lds((as1_uint*)g,
      (as3_uint*)(unsigned int)(uintptr_t)l, 16, 0, 0);
}

__device__ __forceinline__ unsigned cvtpk(float lo, float hi) {
  unsigned r;
  asm("v_cvt_pk_bf16_f32 %0, %1, %2" : "=v"(r) : "v"(lo), "v"(hi));
  return r;
}
__device__ __forceinline__ void plswap(unsigned &a, unsigned &b) {
  asm("v_permlane32_swap_b32 %0, %1" : "+v"(a), "+v"(b));
}

__device__ __forceinline__ void build_pfrag(const f32x16 &s, bf16x8 &f0, bf16x8 &f1) {
  unsigned x0 = cvtpk(s[0], s[1]),  x1 = cvtpk(s[2], s[3]);
  unsigned x2 = cvtpk(s[4], s[5]),  x3 = cvtpk(s[6], s[7]);
  plswap(x0, x2); plswap(x1, x3);
  unsigned y0 = cvtpk(s[8], s[9]),  y1 = cvtpk(s[10], s[11]);
  unsigned y2 = cvtpk(s[12], s[13]), y3 = cvtpk(s[14], s[15]);
  plswap(y0, y2); plswap(y1, y3);
  u32x4 a = {x0, x1, x2, x3}, b = {y0, y1, y2, y3};
  f0 = __builtin_bit_cast(bf16x8, a);
  f1 = __builtin_bit_cast(bf16x8, b);
}

// ---------------------------------------------------------------------------
// Kernel 1: fused prep.  Blocks [0,4096): cast x fp32 -> bf16 [4096][1024].
// Blocks [4096,8192): fold LoRA, W'[p] = W_p + B_p@A_p (fp32 -> bf16).
// ---------------------------------------------------------------------------
__global__ void prep_kernel(const float* __restrict__ x, short* __restrict__ xb,
                            const float* __restrict__ wq, const float* __restrict__ wk,
                            const float* __restrict__ wv, const float* __restrict__ wo,
                            const float* __restrict__ bq, const float* __restrict__ bk,
                            const float* __restrict__ bv, const float* __restrict__ bo,
                            const float* __restrict__ aq, const float* __restrict__ ak,
                            const float* __restrict__ av, const float* __restrict__ ao,
                            short* __restrict__ wbo) {
  const int b = blockIdx.x;
  if (b < 4096) {
    const int idx = b * 256 + threadIdx.x;
    f32x4 v = ((const f32x4*)x)[idx];
    u16x4 o;
    o[0] = (unsigned short)f2bf(v[0]);
    o[1] = (unsigned short)f2bf(v[1]);
    o[2] = (unsigned short)f2bf(v[2]);
    o[3] = (unsigned short)f2bf(v[3]);
    ((u16x4*)xb)[idx] = o;
  } else {
    const int bb = b - 4096;
    const int p = bb >> 10;
    const float* W  = (p == 0) ? wq : (p == 1) ? wk : (p == 2) ? wv : wo;
    const float* Bm = (p == 0) ? bq : (p == 1) ? bk : (p == 2) ? bv : bo;
    const float* A  = (p == 0) ? aq : (p == 1) ? ak : (p == 2) ? av : ao;
    const int idx = (bb & 1023) * 256 + threadIdx.x;
    const int n = idx >> 8;
    const int e4 = idx & 255;
    f32x4 acc = ((const f32x4*)(W + (size_t)n * 1024))[e4];
    const float* br = Bm + n * 16;
    #pragma unroll
    for (int r = 0; r < 16; ++r) {
      const f32x4 a4 = ((const f32x4*)(A + (size_t)r * 1024))[e4];
      const float bl = br[r];
      acc[0] += bl * a4[0];
      acc[1] += bl * a4[1];
      acc[2] += bl * a4[2];
      acc[3] += bl * a4[3];
    }
    u16x4 o;
    o[0] = (unsigned short)f2bf(acc[0]);
    o[1] = (unsigned short)f2bf(acc[1]);
    o[2] = (unsigned short)f2bf(acc[2]);
    o[3] = (unsigned short)f2bf(acc[3]);
    *(u16x4*)(wbo + (size_t)p * 1048576 + (size_t)idx * 4) = o;
  }
}

// ---------------------------------------------------------------------------
// Kernel 2: merged q/k/v projection, 256x256 tile, 8 waves (2M x 4N),
// 8-phase counted-vmcnt schedule.  Grid 192 = 16 brow x 12 bcol, XCD
// transpose swizzle.  LDS 128 KB = 2buf x 2half x 128x64 x (A,B).
// (unchanged from R16)
// ---------------------------------------------------------------------------
__global__ __launch_bounds__(512, 2)
void gemm_qkv(const short* __restrict__ xb, const short* __restrict__ wb,
              const float* __restrict__ biasq, const float* __restrict__ biask,
              const float* __restrict__ biasv,
              short* __restrict__ qbuf, short* __restrict__ kbuf, short* __restrict__ vtb) {
  __shared__ short Ah[2][2][8192];     // [buf][half][128 rows * 64 cols]
  __shared__ short Bh[2][2][8192];
  const int wg = blockIdx.x;                    // 0..191
  const int swz = (wg & 7) * 24 + (wg >> 3);    // XCD owns 2 brows x 12 bcols
  const int brow = swz / 12, bcol = swz % 12;
  const int tid = threadIdx.x;
  const int wid = tid >> 6, lane = tid & 63;
  const int wr = wid >> 2, wc = wid & 3;        // 2M x 4N wave grid
  const int lrow = lane & 15, lk = lane >> 4;
  const int sl8 = (tid & 7) ^ ((tid >> 3) & 7); // inverse-swizzled source slot

  const short* Asrc = xb + (size_t)brow * 256 * 1024;
  const short* Bsrc = wb + (size_t)bcol * 256 * 1024;

#define STAGE_H(SRC, LDS, hf, kt, buf)                                         \
  { _Pragma("unroll")                                                          \
    for (int i = 0; i < 2; ++i) {                                              \
      const int row = (hf) * 128 + i * 64 + (tid >> 3);                        \
      gload_lds16(SRC + (size_t)row * 1024 + (kt) * 64 + sl8 * 8,              \
                  LDS[buf][hf] + (i * 64 + wid * 8) * 64);                     \
    } }

  const f32x4 fz = {0.f, 0.f, 0.f, 0.f};
  f32x4 acc[8][4];
  #pragma unroll
  for (int a = 0; a < 8; ++a)
    #pragma unroll
    for (int b = 0; b < 4; ++b) acc[a][b] = fz;

  STAGE_H(Asrc, Ah, 0, 0, 0)
  STAGE_H(Asrc, Ah, 1, 0, 0)
  STAGE_H(Bsrc, Bh, 0, 0, 0)
  STAGE_H(Bsrc, Bh, 1, 0, 0)
  STAGE_H(Bsrc, Bh, 0, 1, 1)
  STAGE_H(Bsrc, Bh, 1, 1, 1)
  asm volatile("s_waitcnt vmcnt(4)" ::: "memory");
  __builtin_amdgcn_s_barrier();

  const int bhalf = wc >> 1;
  for (int t = 0; t < 16; ++t) {
    const int cur = t & 1;
    bf16x8 bfr[4][2];
    #pragma unroll
    for (int q = 0; q < 4; ++q) {
      if (q == 0) {
        #pragma unroll
        for (int nj = 0; nj < 4; ++nj) {
          const int rr = (wc & 1) * 64 + nj * 16 + lrow;
          #pragma unroll
          for (int kc = 0; kc < 2; ++kc)
            bfr[nj][kc] = *(const bf16x8*)(&Bh[cur][bhalf][rr * 64 + (((kc * 4 + lk) ^ (rr & 7)) * 8)]);
        }
      }
      bf16x8 afr[2][2];
      #pragma unroll
      for (int m2 = 0; m2 < 2; ++m2) {
        const int rr = q * 32 + m2 * 16 + lrow;
        #pragma unroll
        for (int kc = 0; kc < 2; ++kc)
          afr[m2][kc] = *(const bf16x8*)(&Ah[cur][wr][rr * 64 + (((kc * 4 + lk) ^ (rr & 7)) * 8)]);
      }
      if (q == 0) { if (t + 1 < 16) STAGE_H(Asrc, Ah, 0, t + 1, cur ^ 1) }
      else if (q == 1) { if (t + 1 < 16) STAGE_H(Asrc, Ah, 1, t + 1, cur ^ 1) }
      else if (q == 2) { if (t + 2 < 16) STAGE_H(Bsrc, Bh, 0, t + 2, cur) }
      else             { if (t + 2 < 16) STAGE_H(Bsrc, Bh, 1, t + 2, cur) }

      if (q == 0) asm volatile("s_waitcnt lgkmcnt(8)" ::: "memory");
      __builtin_amdgcn_s_barrier();
      asm volatile("s_waitcnt lgkmcnt(0)" ::: "memory");
      __builtin_amdgcn_s_setprio(1);
      #pragma unroll
      for (int kc = 0; kc < 2; ++kc)
        #pragma unroll
        for (int m2 = 0; m2 < 2; ++m2)
          #pragma unroll
          for (int nj = 0; nj < 4; ++nj)
            acc[q * 2 + m2][nj] = __builtin_amdgcn_mfma_f32_16x16x32_bf16(
                afr[m2][kc], bfr[nj][kc], acc[q * 2 + m2][nj], 0, 0, 0);
      __builtin_amdgcn_s_setprio(0);
      if (q == 3) {
        if (t < 14) asm volatile("s_waitcnt vmcnt(4)" ::: "memory");
        else        asm volatile("s_waitcnt vmcnt(0)" ::: "memory");
      }
      __builtin_amdgcn_s_barrier();
    }
  }
#undef STAGE_H

  const int p = bcol >> 2;
  const float* bias = (p == 0) ? biasq : (p == 1) ? biask : biasv;
  const float oscale = (p == 0) ? 0.18033688f : 1.0f;
  const int c0 = (bcol & 3) * 256 + wc * 64;
  float bcv[4];
  #pragma unroll
  for (int nj = 0; nj < 4; ++nj)
    bcv[nj] = bias[c0 + nj * 16 + lrow];

  #pragma unroll
  for (int mi = 0; mi < 8; ++mi) {
    #pragma unroll
    for (int r = 0; r < 4; ++r) {
      const int gr = brow * 256 + wr * 128 + mi * 16 + lk * 4 + r;   // C/D row
      const int bb = gr >> 10, s = gr & 1023;
      #pragma unroll
      for (int nj = 0; nj < 4; ++nj) {
        const int gc = c0 + nj * 16 + lrow;                          // 0..1023
        const float v = (acc[mi][nj][r] + bcv[nj]) * oscale;
        const int h = gc >> 6, d = gc & 63;
        const int bh = bb * 16 + h;
        if (p == 2)
          vtb[((size_t)bh * 64 + d) * 1024 + s] = f2bf(v);
        else
          ((p == 0) ? qbuf : kbuf)[((size_t)bh * 1024 + s) * 64 + d] = f2bf(v);
      }
    }
  }
}

// ---------------------------------------------------------------------------
// Kernel 3: flash attention, swapped 32x32 MFMA form.
// 8-wave blocks (512 thr, 256 q-rows), grid (64 bh, 4 qt) = 256 blocks.
// 3-buffer LDS ring + counted vmcnt (T4): per tile {STAGE(tt+1)->(tt+1)%3;
// vmcnt(2) (only tile tt's 2 loads awaited); lgkmcnt(0); barrier; compute}.
// Hazards: buf b re-staged at iter b+2; readers (iter b) publish at barrier
// b+1 via lgkmcnt(0).  Consumption after each wave's own vmcnt + barrier.
// ---------------------------------------------------------------------------
__global__ __launch_bounds__(512)
void attn_kernel(const short* __restrict__ qbuf, const short* __restrict__ kbuf,
                 const short* __restrict__ vtb, short* __restrict__ cb) {
  __shared__ short Ks[3][64 * 64];
  __shared__ short Vs[3][64 * 64];
  const int bh = blockIdx.x, qt = blockIdx.y;
  const int tid = threadIdx.x, w = tid >> 6, lane = tid & 63;
  const int l31 = lane & 31, hi = lane >> 5;
  const int srow = lane >> 3, sphys = lane & 7;
  const short* Qp = qbuf + (size_t)bh * 65536;
  const short* Kp = kbuf + (size_t)bh * 65536;
  const short* Vp = vtb + (size_t)bh * 65536;
  const int q0 = qt * 256 + w * 32;

  bf16x8 bq[4];
  #pragma unroll
  for (int kc = 0; kc < 4; ++kc)
    bq[kc] = *(const bf16x8*)(Qp + (size_t)(q0 + l31) * 64 + kc * 16 + hi * 8);

  const f32x16 fz16 = {0.f,0.f,0.f,0.f,0.f,0.f,0.f,0.f,0.f,0.f,0.f,0.f,0.f,0.f,0.f,0.f};
  float m_run = -1e30f, l_run = 0.f;
  f32x16 acc0 = fz16, acc1 = fz16;

  // stage: 8 chunks of 8 rows, one chunk per wave, per matrix (2 loads/thread)
  #define STAGE_KV(buf, tt)                                                  \
    {                                                                        \
      const int t0s = (tt) * 64;                                             \
      const int row = w * 8 + srow;                                          \
      const int sl = sphys ^ (row & 7);                                      \
      gload_lds16(Kp + (size_t)(t0s + row) * 64 + sl * 8, Ks[buf] + w * 512); \
      gload_lds16(Vp + (size_t)row * 1024 + t0s + sl * 8, Vs[buf] + w * 512); \
    }

  STAGE_KV(0, 0);

  int cur = 0, nxt = 1;
  for (int tt = 0; tt < 16; ++tt) {
    if (tt < 15) {
      STAGE_KV(nxt, tt + 1);
      asm volatile("s_waitcnt vmcnt(2)" ::: "memory");   // tile tt landed (mine)
    } else {
      asm volatile("s_waitcnt vmcnt(0)" ::: "memory");
    }
    asm volatile("s_waitcnt lgkmcnt(0)" ::: "memory");   // my prev reads retired
    __builtin_amdgcn_s_barrier();                        // all waves: tile tt ready

    // ---- S^T = K · Q^T ----
    f32x16 s0 = fz16, s1 = fz16;
    __builtin_amdgcn_s_setprio(1);
    #pragma unroll
    for (int kc = 0; kc < 4; ++kc) {
      const int slot = (kc * 2 + hi) ^ (l31 & 7);
      const bf16x8 ak0 = *(const bf16x8*)(Ks[cur] + l31 * 64 + slot * 8);
      const bf16x8 ak1 = *(const bf16x8*)(Ks[cur] + (32 + l31) * 64 + slot * 8);
      s0 = __builtin_amdgcn_mfma_f32_32x32x16_bf16(ak0, bq[kc], s0, 0, 0, 0);
      s1 = __builtin_amdgcn_mfma_f32_32x32x16_bf16(ak1, bq[kc], s1, 0, 0, 0);
    }
    __builtin_amdgcn_s_setprio(0);

    // ---- max: pairwise tree ----
    float t16[16];
    #pragma unroll
    for (int r = 0; r < 8; ++r) t16[r] = fmaxf(s0[2 * r], s0[2 * r + 1]);
    #pragma unroll
    for (int r = 0; r < 8; ++r) t16[8 + r] = fmaxf(s1[2 * r], s1[2 * r + 1]);
    #pragma unroll
    for (int r = 0; r < 8; ++r) t16[r] = fmaxf(t16[r], t16[r + 8]);
    #pragma unroll
    for (int r = 0; r < 4; ++r) t16[r] = fmaxf(t16[r], t16[r + 4]);
    float tm = fmaxf(fmaxf(t16[0], t16[1]), fmaxf(t16[2], t16[3]));
    tm = fmaxf(tm, __shfl_xor(tm, 32, 64));

    // ---- defer-max (T13) ----
    if (__any(tm - m_run > 8.0f)) {
      const float mn = fmaxf(m_run, tm);
      const float alpha = exp2f(m_run - mn);
      m_run = mn;
      l_run *= alpha;
      #pragma unroll
      for (int r = 0; r < 16; ++r) { acc0[r] *= alpha; acc1[r] *= alpha; }
    }

    // ---- P = 2^(S - m), sum via pairwise tree ----
    float a16[16];
    #pragma unroll
    for (int r = 0; r < 16; ++r) { s0[r] = exp2f(s0[r] - m_run); }
    #pragma unroll
    for (int r = 0; r < 16; ++r) { s1[r] = exp2f(s1[r] - m_run); }
    #pragma unroll
    for (int r = 0; r < 8; ++r) a16[r] = s0[2 * r] + s0[2 * r + 1];
    #pragma unroll
    for (int r = 0; r < 8; ++r) a16[8 + r] = s1[2 * r] + s1[2 * r + 1];
    #pragma unroll
    for (int r = 0; r < 8; ++r) a16[r] += a16[r + 8];
    #pragma unroll
    for (int r = 0; r < 4; ++r) a16[r] += a16[r + 4];
    float rs = (a16[0] + a16[1]) + (a16[2] + a16[3]);
    rs += __shfl_xor(rs, 32, 64);
    l_run += rs;

    // ---- P^T fragments (in-register, T12) ----
    bf16x8 pf[4];
    build_pfrag(s0, pf[0], pf[1]);
    build_pfrag(s1, pf[2], pf[3]);

    // ---- O^T += V^T · P^T ----
    __builtin_amdgcn_s_setprio(1);
    #pragma unroll
    for (int kc4 = 0; kc4 < 4; ++kc4) {
      const int slot = (kc4 * 2 + hi) ^ (l31 & 7);
      const bf16x8 av0 = *(const bf16x8*)(Vs[cur] + l31 * 64 + slot * 8);
      const bf16x8 av1 = *(const bf16x8*)(Vs[cur] + (32 + l31) * 64 + slot * 8);
      acc0 = __builtin_amdgcn_mfma_f32_32x32x16_bf16(av0, pf[kc4], acc0, 0, 0, 0);
      acc1 = __builtin_amdgcn_mfma_f32_32x32x16_bf16(av1, pf[kc4], acc1, 0, 0, 0);
    }
    __builtin_amdgcn_s_setprio(0);

    cur = (cur == 2) ? 0 : (cur + 1);
    nxt = (nxt == 2) ? 0 : (nxt + 1);
  }

  const int bb = bh >> 4, h = bh & 15;
  const int s = q0 + l31;
  short* crow = cb + (size_t)(bb * 1024 + s) * 1024 + h * 64;
  const float inv = 1.f / l_run;
  #pragma unroll
  for (int rp = 0; rp < 8; ++rp) {
    const int r = rp * 2;
    const int d = (r & 3) + 8 * (r >> 2) + 4 * hi;
    const unsigned p0 = (unsigned)(unsigned short)f2bf(acc0[r] * inv)
                      | ((unsigned)(unsigned short)f2bf(acc0[r + 1] * inv) << 16);
    const unsigned p1 = (unsigned)(unsigned short)f2bf(acc1[r] * inv)
                      | ((unsigned)(unsigned short)f2bf(acc1[r + 1] * inv) << 16);
    *(unsigned*)(crow + d) = p0;
    *(unsigned*)(crow + 32 + d) = p1;
  }
  #undef STAGE_KV
}

// ---------------------------------------------------------------------------
// GEMM core, depth-2 counted-vmcnt pipeline (gemm_o).
// ---------------------------------------------------------------------------
__device__ __forceinline__ void gemm_core_p3(const short* __restrict__ xrow,
                                             const short* __restrict__ wrow,
                                             short (&As)[3][8192], short (&Bs)[3][8192],
                                             f32x4 (&acc)[4][4]) {
  const int tid = threadIdx.x;
  const int wv = tid >> 6, lane = tid & 63;
  const int wr = wv >> 1, wc = wv & 1;
  const int lrow = lane & 15, lk = lane >> 4;
  const int srow = lane >> 3, sphys = lane & 7;

#define STAGE_G(buf, kt)                                                       \
  {                                                                            \
    _Pragma("unroll")                                                          \
    for (int i = 0; i < 4; ++i) {                                              \
      const int ch = i * 4 + wv;                                               \
      const int row = ch * 8 + srow;                                           \
      const int sl = sphys ^ (row & 7);                                        \
      gload_lds16(xrow + (size_t)row * 1024 + (kt) * 64 + sl * 8, As[buf] + ch * 512); \
      gload_lds16(wrow + (size_t)row * 1024 + (kt) * 64 + sl * 8, Bs[buf] + ch * 512); \
    }                                                                          \
  }

  STAGE_G(0, 0);
  STAGE_G(1, 1);
  int cur = 0;
  for (int kt = 0; kt < 16; ++kt) {
    if (kt < 14) {
      const int nb = (cur == 0) ? 2 : (cur - 1);   // (kt+2)%3
      STAGE_G(nb, kt + 2);
      asm volatile("s_waitcnt vmcnt(16)" ::: "memory");
    } else if (kt == 14) {
      asm volatile("s_waitcnt vmcnt(8)" ::: "memory");
    } else {
      asm volatile("s_waitcnt vmcnt(0)" ::: "memory");
    }
    __builtin_amdgcn_s_barrier();

    #pragma unroll
    for (int kc = 0; kc < 2; ++kc) {
      bf16x8 af[4], bw[4];
      #pragma unroll
      for (int mi = 0; mi < 4; ++mi) {
        const int row = wr * 64 + mi * 16 + lrow;
        const int slot = (kc * 4 + lk) ^ (row & 7);
        af[mi] = *(const bf16x8*)(As[cur] + row * 64 + slot * 8);
      }
      #pragma unroll
      for (int nj = 0; nj < 4; ++nj) {
        const int row = wc * 64 + nj * 16 + lrow;
        const int slot = (kc * 4 + lk) ^ (row & 7);
        bw[nj] = *(const bf16x8*)(Bs[cur] + row * 64 + slot * 8);
      }
      __builtin_amdgcn_s_setprio(1);
      #pragma unroll
      for (int mi = 0; mi < 4; ++mi)
        #pragma unroll
        for (int nj = 0; nj < 4; ++nj)
          acc[mi][nj] = __builtin_amdgcn_mfma_f32_16x16x32_bf16(af[mi], bw[nj], acc[mi][nj], 0, 0, 0);
      __builtin_amdgcn_s_setprio(0);
    }

    asm volatile("s_waitcnt lgkmcnt(0)" ::: "memory");
    __builtin_amdgcn_s_barrier();
    cur = (cur == 2) ? 0 : (cur + 1);
  }
#undef STAGE_G
}

// ---------------------------------------------------------------------------
// Kernel 4: o-projection -> fp32 d_out (p3 core, grid 256 = 1/CU).
// ---------------------------------------------------------------------------
__global__ __launch_bounds__(256)
void gemm_o(const short* __restrict__ cb, const short* __restrict__ wo,
            const float* __restrict__ biaso, float* __restrict__ out) {
  __shared__ short As[3][8192];
  __shared__ short Bs[3][8192];
  const int brow = blockIdx.y, bcol = blockIdx.x;
  const f32x4 fz = {0.f, 0.f, 0.f, 0.f};
  f32x4 acc[4][4];
  #pragma unroll
  for (int a = 0; a < 4; ++a)
    #pragma unroll
    for (int b = 0; b < 4; ++b) acc[a][b] = fz;

  gemm_core_p3(cb + (size_t)brow * 128 * 1024, wo + (size_t)bcol * 128 * 1024,
               As, Bs, acc);

  const int tid = threadIdx.x;
  const int wv = tid >> 6, lane = tid & 63;
  const int wr = wv >> 1, wc = wv & 1;
  const int lrow = lane & 15, lk = lane >> 4;
  float bcv[4];
  #pragma unroll
  for (int nj = 0; nj < 4; ++nj)
    bcv[nj] = biaso[bcol * 128 + wc * 64 + nj * 16 + lrow];

  #pragma unroll
  for (int mi = 0; mi < 4; ++mi) {
    #pragma unroll
    for (int r = 0; r < 4; ++r) {
      const int gr = brow * 128 + wr * 64 + mi * 16 + lk * 4 + r;
      #pragma unroll
      for (int nj = 0; nj < 4; ++nj) {
        const int gc = bcol * 128 + wc * 64 + nj * 16 + lrow;
        out[(size_t)gr * 1024 + gc] = acc[mi][nj][r] + bcv[nj];
      }
    }
  }
}

// ---------------------------------------------------------------------------
extern "C" void kernel_launch(void* const* d_in, const int* in_sizes, int n_in,
                              void* d_out, int out_size, void* d_ws, size_t ws_size,
                              hipStream_t stream) {
  (void)in_sizes; (void)n_in; (void)out_size; (void)ws_size;
  const float* x   = (const float*)d_in[0];
  const float* qw  = (const float*)d_in[1];
  const float* qb  = (const float*)d_in[2];
  const float* qla = (const float*)d_in[3];
  const float* qlb = (const float*)d_in[4];
  const float* kw  = (const float*)d_in[5];
  const float* kb  = (const float*)d_in[6];
  const float* kla = (const float*)d_in[7];
  const float* klb = (const float*)d_in[8];
  const float* vw  = (const float*)d_in[9];
  const float* vb  = (const float*)d_in[10];
  const float* vla = (const float*)d_in[11];
  const float* vlb = (const float*)d_in[12];
  const float* ow  = (const float*)d_in[13];
  const float* ob  = (const float*)d_in[14];
  const float* ola = (const float*)d_in[15];
  const float* olb = (const float*)d_in[16];

  short* xb   = (short*)d_ws;                         // 4096*1024 bf16 (reused as ctx)
  short* wb   = xb + (size_t)4096 * 1024;             // 4*1024*1024 bf16
  short* qbuf = wb + (size_t)4 * 1024 * 1024;         // 64*1024*64 each
  short* kbuf = qbuf + (size_t)4194304;
  short* vtb  = kbuf + (size_t)4194304;               // total 40 MB

  prep_kernel<<<8192, 256, 0, stream>>>(x, xb, qw, kw, vw, ow,
                                        qlb, klb, vlb, olb,
                                        qla, kla, vla, ola, wb);
  gemm_qkv<<<192, 512, 0, stream>>>(xb, wb, qb, kb, vb, qbuf, kbuf, vtb);
  attn_kernel<<<dim3(64, 4), 512, 0, stream>>>(qbuf, kbuf, vtb, xb);
  gemm_o<<<dim3(8, 32), 256, 0, stream>>>(xb, wb + (size_t)3 * 1024 * 1024, ob, (float*)d_out);
}

// Round 18
// 121.711 us; speedup vs baseline: 1.0918x; 1.0564x over previous
//
#include <hip/hip_runtime.h>
#include <cstdint>

// ---------------------------------------------------------------------------
// LoRA MHA: B=4,S=1024,E=1024,H=16,D=64,R=16.  bf16 MFMA, fp32 accum.
// LoRA folded into the weights: W' = W + B@A (scale=1).
// R18: gemm_qkv 8-phase kernel retiled 256x256 -> 256x192 so grid = 16x16 =
// 256 blocks = 100% CU fill (was 192 = 75%).  Per-block: 12 MFMA/phase,
// B staged as 3 x 64-row one-load chunks (q2,q2,q3), window-end vmcnt(3).
// Epilogue computes projection p per column (tiles cross the 1024 boundary).
// attn (counted-vmcnt ring), gemm_o (p3), prep unchanged from R17.
// ---------------------------------------------------------------------------

typedef __attribute__((ext_vector_type(8))) short bf16x8;
typedef __attribute__((ext_vector_type(4))) float f32x4;
typedef __attribute__((ext_vector_type(16))) float f32x16;
typedef __attribute__((ext_vector_type(4))) unsigned short u16x4;
typedef __attribute__((ext_vector_type(4))) unsigned int u32x4;

__device__ __forceinline__ short f2bf(float f) {
  unsigned u = __builtin_bit_cast(unsigned, f);
  u += 0x7FFFu + ((u >> 16) & 1u);          // RNE
  return (short)(u >> 16);
}

typedef __attribute__((address_space(1))) const unsigned int as1_uint;
typedef __attribute__((address_space(3))) unsigned int as3_uint;

__device__ __forceinline__ void gload_lds16(const short* g, const short* l) {
  __builtin_amdgcn_global_load_lds((as1_uint*)g,
      (as3_uint*)(unsigned int)(uintptr_t)l, 16, 0, 0);
}

__device__ __forceinline__ unsigned cvtpk(float lo, float hi) {
  unsigned r;
  asm("v_cvt_pk_bf16_f32 %0, %1, %2" : "=v"(r) : "v"(lo), "v"(hi));
  return r;
}
__device__ __forceinline__ void plswap(unsigned &a, unsigned &b) {
  asm("v_permlane32_swap_b32 %0, %1" : "+v"(a), "+v"(b));
}

__device__ __forceinline__ void build_pfrag(const f32x16 &s, bf16x8 &f0, bf16x8 &f1) {
  unsigned x0 = cvtpk(s[0], s[1]),  x1 = cvtpk(s[2], s[3]);
  unsigned x2 = cvtpk(s[4], s[5]),  x3 = cvtpk(s[6], s[7]);
  plswap(x0, x2); plswap(x1, x3);
  unsigned y0 = cvtpk(s[8], s[9]),  y1 = cvtpk(s[10], s[11]);
  unsigned y2 = cvtpk(s[12], s[13]), y3 = cvtpk(s[14], s[15]);
  plswap(y0, y2); plswap(y1, y3);
  u32x4 a = {x0, x1, x2, x3}, b = {y0, y1, y2, y3};
  f0 = __builtin_bit_cast(bf16x8, a);
  f1 = __builtin_bit_cast(bf16x8, b);
}

// ---------------------------------------------------------------------------
// Kernel 1: fused prep.  Blocks [0,4096): cast x fp32 -> bf16 [4096][1024].
// Blocks [4096,8192): fold LoRA, W'[p] = W_p + B_p@A_p (fp32 -> bf16).
// ---------------------------------------------------------------------------
__global__ void prep_kernel(const float* __restrict__ x, short* __restrict__ xb,
                            const float* __restrict__ wq, const float* __restrict__ wk,
                            const float* __restrict__ wv, const float* __restrict__ wo,
                            const float* __restrict__ bq, const float* __restrict__ bk,
                            const float* __restrict__ bv, const float* __restrict__ bo,
                            const float* __restrict__ aq, const float* __restrict__ ak,
                            const float* __restrict__ av, const float* __restrict__ ao,
                            short* __restrict__ wbo) {
  const int b = blockIdx.x;
  if (b < 4096) {
    const int idx = b * 256 + threadIdx.x;
    f32x4 v = ((const f32x4*)x)[idx];
    u16x4 o;
    o[0] = (unsigned short)f2bf(v[0]);
    o[1] = (unsigned short)f2bf(v[1]);
    o[2] = (unsigned short)f2bf(v[2]);
    o[3] = (unsigned short)f2bf(v[3]);
    ((u16x4*)xb)[idx] = o;
  } else {
    const int bb = b - 4096;
    const int p = bb >> 10;
    const float* W  = (p == 0) ? wq : (p == 1) ? wk : (p == 2) ? wv : wo;
    const float* Bm = (p == 0) ? bq : (p == 1) ? bk : (p == 2) ? bv : bo;
    const float* A  = (p == 0) ? aq : (p == 1) ? ak : (p == 2) ? av : ao;
    const int idx = (bb & 1023) * 256 + threadIdx.x;
    const int n = idx >> 8;
    const int e4 = idx & 255;
    f32x4 acc = ((const f32x4*)(W + (size_t)n * 1024))[e4];
    const float* br = Bm + n * 16;
    #pragma unroll
    for (int r = 0; r < 16; ++r) {
      const f32x4 a4 = ((const f32x4*)(A + (size_t)r * 1024))[e4];
      const float bl = br[r];
      acc[0] += bl * a4[0];
      acc[1] += bl * a4[1];
      acc[2] += bl * a4[2];
      acc[3] += bl * a4[3];
    }
    u16x4 o;
    o[0] = (unsigned short)f2bf(acc[0]);
    o[1] = (unsigned short)f2bf(acc[1]);
    o[2] = (unsigned short)f2bf(acc[2]);
    o[3] = (unsigned short)f2bf(acc[3]);
    *(u16x4*)(wbo + (size_t)p * 1048576 + (size_t)idx * 4) = o;
  }
}

// ---------------------------------------------------------------------------
// Kernel 2: merged q/k/v projection, 256x192 tile, 8 waves (2M x 4N),
// 8-phase counted-vmcnt schedule.  Grid 256 = 16 brow x 16 bcol (100% CU
// fill), XCD swizzle (2 brows x 16 bcols per XCD).
// LDS: A 2buf x 2half x [128][64] = 64 KB ; B 2buf x [192][64] = 48 KB.
// Window t (4 phases) computes K-tile t:
//   q0: [3x2 B-frag + 4 A-frag ds_reads] stage A-half0(t+1)->buf^1 (2 ld)
//   q1: [4 A-frag]                        stage A-half1(t+1)->buf^1 (2 ld)
//   q2: [4 A-frag]                        stage B-chunk0+1(t+2)->cur (2 ld)
//   q3: [4 A-frag]                        stage B-chunk2(t+2)->cur  (1 ld)
//   each phase: barrier; lgkm(0); setprio 12 MFMA; [q3: vmcnt(3)]; barrier
// vmcnt(3): only B(t+2)'s 3 loads may remain -> A(t+1),B(t+1) landed.
// ---------------------------------------------------------------------------
__global__ __launch_bounds__(512, 1)
void gemm_qkv(const short* __restrict__ xb, const short* __restrict__ wb,
              const float* __restrict__ biasq, const float* __restrict__ biask,
              const float* __restrict__ biasv,
              short* __restrict__ qbuf, short* __restrict__ kbuf, short* __restrict__ vtb) {
  __shared__ short Ah[2][2][8192];     // [buf][half][128 rows * 64 cols]
  __shared__ short Bf[2][12288];       // [buf][192 rows * 64 cols]
  const int wg = blockIdx.x;                    // 0..255
  const int swz = (wg & 7) * 32 + (wg >> 3);    // XCD owns 2 brows x 16 bcols
  const int brow = swz >> 4, bcol = swz & 15;
  const int tid = threadIdx.x;
  const int wid = tid >> 6, lane = tid & 63;
  const int wr = wid >> 2, wc = wid & 3;        // 2M x 4N wave grid
  const int lrow = lane & 15, lk = lane >> 4;
  const int sl8 = (tid & 7) ^ ((tid >> 3) & 7); // inverse-swizzled source slot

  const short* Asrc = xb + (size_t)brow * 256 * 1024;
  const short* Bsrc = wb + (size_t)bcol * 192 * 1024;

  // A half-tile (128 rows x 64 cols), 2 loads/thread
#define STAGE_A(hf, kt, buf)                                                   \
  { _Pragma("unroll")                                                          \
    for (int i = 0; i < 2; ++i) {                                              \
      const int row = (hf) * 128 + i * 64 + (tid >> 3);                        \
      gload_lds16(Asrc + (size_t)row * 1024 + (kt) * 64 + sl8 * 8,             \
                  Ah[buf][hf] + (i * 64 + wid * 8) * 64);                      \
    } }
  // B chunk (64 rows x 64 cols), 1 load/thread
#define STAGE_B(ch, kt, buf)                                                   \
  {                                                                            \
    const int row = (ch) * 64 + (tid >> 3);                                    \
    gload_lds16(Bsrc + (size_t)row * 1024 + (kt) * 64 + sl8 * 8,               \
                Bf[buf] + (ch) * 4096 + tid * 8);                              \
  }

  const f32x4 fz = {0.f, 0.f, 0.f, 0.f};
  f32x4 acc[8][3];
  #pragma unroll
  for (int a = 0; a < 8; ++a)
    #pragma unroll
    for (int b = 0; b < 3; ++b) acc[a][b] = fz;

  // prologue: A(0) 4 loads + B(0) 3 + B(1) 3 ; wait A(0),B(0) landed
  STAGE_A(0, 0, 0)
  STAGE_A(1, 0, 0)
  STAGE_B(0, 0, 0) STAGE_B(1, 0, 0) STAGE_B(2, 0, 0)
  STAGE_B(0, 1, 1) STAGE_B(1, 1, 1) STAGE_B(2, 1, 1)
  asm volatile("s_waitcnt vmcnt(3)" ::: "memory");
  __builtin_amdgcn_s_barrier();

  for (int t = 0; t < 16; ++t) {
    const int cur = t & 1;
    bf16x8 bfr[3][2];                   // B frags live across the window
    #pragma unroll
    for (int q = 0; q < 4; ++q) {
      if (q == 0) {
        #pragma unroll
        for (int nj = 0; nj < 3; ++nj) {
          const int rr = wc * 48 + nj * 16 + lrow;
          #pragma unroll
          for (int kc = 0; kc < 2; ++kc)
            bfr[nj][kc] = *(const bf16x8*)(&Bf[cur][rr * 64 + (((kc * 4 + lk) ^ (rr & 7)) * 8)]);
        }
      }
      bf16x8 afr[2][2];
      #pragma unroll
      for (int m2 = 0; m2 < 2; ++m2) {
        const int rr = q * 32 + m2 * 16 + lrow;
        #pragma unroll
        for (int kc = 0; kc < 2; ++kc)
          afr[m2][kc] = *(const bf16x8*)(&Ah[cur][wr][rr * 64 + (((kc * 4 + lk) ^ (rr & 7)) * 8)]);
      }
      if (q == 0)      { if (t + 1 < 16) STAGE_A(0, t + 1, cur ^ 1) }
      else if (q == 1) { if (t + 1 < 16) STAGE_A(1, t + 1, cur ^ 1) }
      else if (q == 2) { if (t + 2 < 16) { STAGE_B(0, t + 2, cur) STAGE_B(1, t + 2, cur) } }
      else             { if (t + 2 < 16) STAGE_B(2, t + 2, cur) }

      if (q == 0) asm volatile("s_waitcnt lgkmcnt(6)" ::: "memory");
      __builtin_amdgcn_s_barrier();
      asm volatile("s_waitcnt lgkmcnt(0)" ::: "memory");
      __builtin_amdgcn_s_setprio(1);
      #pragma unroll
      for (int kc = 0; kc < 2; ++kc)
        #pragma unroll
        for (int m2 = 0; m2 < 2; ++m2)
          #pragma unroll
          for (int nj = 0; nj < 3; ++nj)
            acc[q * 2 + m2][nj] = __builtin_amdgcn_mfma_f32_16x16x32_bf16(
                afr[m2][kc], bfr[nj][kc], acc[q * 2 + m2][nj], 0, 0, 0);
      __builtin_amdgcn_s_setprio(0);
      if (q == 3) {
        if (t < 14) asm volatile("s_waitcnt vmcnt(3)" ::: "memory");
        else        asm volatile("s_waitcnt vmcnt(0)" ::: "memory");
      }
      __builtin_amdgcn_s_barrier();
    }
  }
#undef STAGE_A
#undef STAGE_B

  // epilogue: projection p varies per column (tiles cross the 1024 boundary)
  const float SCALE = 0.18033688f;   // log2(e)/8 folded into q
  #pragma unroll
  for (int mi = 0; mi < 8; ++mi) {
    #pragma unroll
    for (int r = 0; r < 4; ++r) {
      const int gr = brow * 256 + wr * 128 + mi * 16 + lk * 4 + r;   // C/D row
      const int bb = gr >> 10, s = gr & 1023;
      #pragma unroll
      for (int nj = 0; nj < 3; ++nj) {
        const int gc = bcol * 192 + wc * 48 + nj * 16 + lrow;        // 0..3071
        const int p = gc >> 10, pc = gc & 1023;
        const float bv = ((p == 0) ? biasq : (p == 1) ? biask : biasv)[pc];
        const float v = (acc[mi][nj][r] + bv) * ((p == 0) ? SCALE : 1.0f);
        const int h = pc >> 6, d = pc & 63;
        const int bh = bb * 16 + h;
        if (p == 2)
          vtb[((size_t)bh * 64 + d) * 1024 + s] = f2bf(v);
        else
          ((p == 0) ? qbuf : kbuf)[((size_t)bh * 1024 + s) * 64 + d] = f2bf(v);
      }
    }
  }
}

// ---------------------------------------------------------------------------
// Kernel 3: flash attention, swapped 32x32 MFMA form (unchanged from R17).
// 8-wave blocks (512 thr, 256 q-rows), grid (64 bh, 4 qt) = 256 blocks.
// 3-buffer LDS ring + counted vmcnt (T4).
// ---------------------------------------------------------------------------
__global__ __launch_bounds__(512)
void attn_kernel(const short* __restrict__ qbuf, const short* __restrict__ kbuf,
                 const short* __restrict__ vtb, short* __restrict__ cb) {
  __shared__ short Ks[3][64 * 64];
  __shared__ short Vs[3][64 * 64];
  const int bh = blockIdx.x, qt = blockIdx.y;
  const int tid = threadIdx.x, w = tid >> 6, lane = tid & 63;
  const int l31 = lane & 31, hi = lane >> 5;
  const int srow = lane >> 3, sphys = lane & 7;
  const short* Qp = qbuf + (size_t)bh * 65536;
  const short* Kp = kbuf + (size_t)bh * 65536;
  const short* Vp = vtb + (size_t)bh * 65536;
  const int q0 = qt * 256 + w * 32;

  bf16x8 bq[4];
  #pragma unroll
  for (int kc = 0; kc < 4; ++kc)
    bq[kc] = *(const bf16x8*)(Qp + (size_t)(q0 + l31) * 64 + kc * 16 + hi * 8);

  const f32x16 fz16 = {0.f,0.f,0.f,0.f,0.f,0.f,0.f,0.f,0.f,0.f,0.f,0.f,0.f,0.f,0.f,0.f};
  float m_run = -1e30f, l_run = 0.f;
  f32x16 acc0 = fz16, acc1 = fz16;

  #define STAGE_KV(buf, tt)                                                  \
    {                                                                        \
      const int t0s = (tt) * 64;                                             \
      const int row = w * 8 + srow;                                          \
      const int sl = sphys ^ (row & 7);                                      \
      gload_lds16(Kp + (size_t)(t0s + row) * 64 + sl * 8, Ks[buf] + w * 512); \
      gload_lds16(Vp + (size_t)row * 1024 + t0s + sl * 8, Vs[buf] + w * 512); \
    }

  STAGE_KV(0, 0);

  int cur = 0, nxt = 1;
  for (int tt = 0; tt < 16; ++tt) {
    if (tt < 15) {
      STAGE_KV(nxt, tt + 1);
      asm volatile("s_waitcnt vmcnt(2)" ::: "memory");   // tile tt landed (mine)
    } else {
      asm volatile("s_waitcnt vmcnt(0)" ::: "memory");
    }
    asm volatile("s_waitcnt lgkmcnt(0)" ::: "memory");   // my prev reads retired
    __builtin_amdgcn_s_barrier();                        // all waves: tile tt ready

    // ---- S^T = K · Q^T ----
    f32x16 s0 = fz16, s1 = fz16;
    __builtin_amdgcn_s_setprio(1);
    #pragma unroll
    for (int kc = 0; kc < 4; ++kc) {
      const int slot = (kc * 2 + hi) ^ (l31 & 7);
      const bf16x8 ak0 = *(const bf16x8*)(Ks[cur] + l31 * 64 + slot * 8);
      const bf16x8 ak1 = *(const bf16x8*)(Ks[cur] + (32 + l31) * 64 + slot * 8);
      s0 = __builtin_amdgcn_mfma_f32_32x32x16_bf16(ak0, bq[kc], s0, 0, 0, 0);
      s1 = __builtin_amdgcn_mfma_f32_32x32x16_bf16(ak1, bq[kc], s1, 0, 0, 0);
    }
    __builtin_amdgcn_s_setprio(0);

    // ---- max: pairwise tree ----
    float t16[16];
    #pragma unroll
    for (int r = 0; r < 8; ++r) t16[r] = fmaxf(s0[2 * r], s0[2 * r + 1]);
    #pragma unroll
    for (int r = 0; r < 8; ++r) t16[8 + r] = fmaxf(s1[2 * r], s1[2 * r + 1]);
    #pragma unroll
    for (int r = 0; r < 8; ++r) t16[r] = fmaxf(t16[r], t16[r + 8]);
    #pragma unroll
    for (int r = 0; r < 4; ++r) t16[r] = fmaxf(t16[r], t16[r + 4]);
    float tm = fmaxf(fmaxf(t16[0], t16[1]), fmaxf(t16[2], t16[3]));
    tm = fmaxf(tm, __shfl_xor(tm, 32, 64));

    // ---- defer-max (T13) ----
    if (__any(tm - m_run > 8.0f)) {
      const float mn = fmaxf(m_run, tm);
      const float alpha = exp2f(m_run - mn);
      m_run = mn;
      l_run *= alpha;
      #pragma unroll
      for (int r = 0; r < 16; ++r) { acc0[r] *= alpha; acc1[r] *= alpha; }
    }

    // ---- P = 2^(S - m), sum via pairwise tree ----
    float a16[16];
    #pragma unroll
    for (int r = 0; r < 16; ++r) { s0[r] = exp2f(s0[r] - m_run); }
    #pragma unroll
    for (int r = 0; r < 16; ++r) { s1[r] = exp2f(s1[r] - m_run); }
    #pragma unroll
    for (int r = 0; r < 8; ++r) a16[r] = s0[2 * r] + s0[2 * r + 1];
    #pragma unroll
    for (int r = 0; r < 8; ++r) a16[8 + r] = s1[2 * r] + s1[2 * r + 1];
    #pragma unroll
    for (int r = 0; r < 8; ++r) a16[r] += a16[r + 8];
    #pragma unroll
    for (int r = 0; r < 4; ++r) a16[r] += a16[r + 4];
    float rs = (a16[0] + a16[1]) + (a16[2] + a16[3]);
    rs += __shfl_xor(rs, 32, 64);
    l_run += rs;

    // ---- P^T fragments (in-register, T12) ----
    bf16x8 pf[4];
    build_pfrag(s0, pf[0], pf[1]);
    build_pfrag(s1, pf[2], pf[3]);

    // ---- O^T += V^T · P^T ----
    __builtin_amdgcn_s_setprio(1);
    #pragma unroll
    for (int kc4 = 0; kc4 < 4; ++kc4) {
      const int slot = (kc4 * 2 + hi) ^ (l31 & 7);
      const bf16x8 av0 = *(const bf16x8*)(Vs[cur] + l31 * 64 + slot * 8);
      const bf16x8 av1 = *(const bf16x8*)(Vs[cur] + (32 + l31) * 64 + slot * 8);
      acc0 = __builtin_amdgcn_mfma_f32_32x32x16_bf16(av0, pf[kc4], acc0, 0, 0, 0);
      acc1 = __builtin_amdgcn_mfma_f32_32x32x16_bf16(av1, pf[kc4], acc1, 0, 0, 0);
    }
    __builtin_amdgcn_s_setprio(0);

    cur = (cur == 2) ? 0 : (cur + 1);
    nxt = (nxt == 2) ? 0 : (nxt + 1);
  }

  const int bb = bh >> 4, h = bh & 15;
  const int s = q0 + l31;
  short* crow = cb + (size_t)(bb * 1024 + s) * 1024 + h * 64;
  const float inv = 1.f / l_run;
  #pragma unroll
  for (int rp = 0; rp < 8; ++rp) {
    const int r = rp * 2;
    const int d = (r & 3) + 8 * (r >> 2) + 4 * hi;
    const unsigned p0 = (unsigned)(unsigned short)f2bf(acc0[r] * inv)
                      | ((unsigned)(unsigned short)f2bf(acc0[r + 1] * inv) << 16);
    const unsigned p1 = (unsigned)(unsigned short)f2bf(acc1[r] * inv)
                      | ((unsigned)(unsigned short)f2bf(acc1[r + 1] * inv) << 16);
    *(unsigned*)(crow + d) = p0;
    *(unsigned*)(crow + 32 + d) = p1;
  }
  #undef STAGE_KV
}

// ---------------------------------------------------------------------------
// GEMM core, depth-2 counted-vmcnt pipeline (gemm_o).
// ---------------------------------------------------------------------------
__device__ __forceinline__ void gemm_core_p3(const short* __restrict__ xrow,
                                             const short* __restrict__ wrow,
                                             short (&As)[3][8192], short (&Bs)[3][8192],
                                             f32x4 (&acc)[4][4]) {
  const int tid = threadIdx.x;
  const int wv = tid >> 6, lane = tid & 63;
  const int wr = wv >> 1, wc = wv & 1;
  const int lrow = lane & 15, lk = lane >> 4;
  const int srow = lane >> 3, sphys = lane & 7;

#define STAGE_G(buf, kt)                                                       \
  {                                                                            \
    _Pragma("unroll")                                                          \
    for (int i = 0; i < 4; ++i) {                                              \
      const int ch = i * 4 + wv;                                               \
      const int row = ch * 8 + srow;                                           \
      const int sl = sphys ^ (row & 7);                                        \
      gload_lds16(xrow + (size_t)row * 1024 + (kt) * 64 + sl * 8, As[buf] + ch * 512); \
      gload_lds16(wrow + (size_t)row * 1024 + (kt) * 64 + sl * 8, Bs[buf] + ch * 512); \
    }                                                                          \
  }

  STAGE_G(0, 0);
  STAGE_G(1, 1);
  int cur = 0;
  for (int kt = 0; kt < 16; ++kt) {
    if (kt < 14) {
      const int nb = (cur == 0) ? 2 : (cur - 1);   // (kt+2)%3
      STAGE_G(nb, kt + 2);
      asm volatile("s_waitcnt vmcnt(16)" ::: "memory");
    } else if (kt == 14) {
      asm volatile("s_waitcnt vmcnt(8)" ::: "memory");
    } else {
      asm volatile("s_waitcnt vmcnt(0)" ::: "memory");
    }
    __builtin_amdgcn_s_barrier();

    #pragma unroll
    for (int kc = 0; kc < 2; ++kc) {
      bf16x8 af[4], bw[4];
      #pragma unroll
      for (int mi = 0; mi < 4; ++mi) {
        const int row = wr * 64 + mi * 16 + lrow;
        const int slot = (kc * 4 + lk) ^ (row & 7);
        af[mi] = *(const bf16x8*)(As[cur] + row * 64 + slot * 8);
      }
      #pragma unroll
      for (int nj = 0; nj < 4; ++nj) {
        const int row = wc * 64 + nj * 16 + lrow;
        const int slot = (kc * 4 + lk) ^ (row & 7);
        bw[nj] = *(const bf16x8*)(Bs[cur] + row * 64 + slot * 8);
      }
      __builtin_amdgcn_s_setprio(1);
      #pragma unroll
      for (int mi = 0; mi < 4; ++mi)
        #pragma unroll
        for (int nj = 0; nj < 4; ++nj)
          acc[mi][nj] = __builtin_amdgcn_mfma_f32_16x16x32_bf16(af[mi], bw[nj], acc[mi][nj], 0, 0, 0);
      __builtin_amdgcn_s_setprio(0);
    }

    asm volatile("s_waitcnt lgkmcnt(0)" ::: "memory");
    __builtin_amdgcn_s_barrier();
    cur = (cur == 2) ? 0 : (cur + 1);
  }
#undef STAGE_G
}

// ---------------------------------------------------------------------------
// Kernel 4: o-projection -> fp32 d_out (p3 core, grid 256 = 1/CU).
// ---------------------------------------------------------------------------
__global__ __launch_bounds__(256)
void gemm_o(const short* __restrict__ cb, const short* __restrict__ wo,
            const float* __restrict__ biaso, float* __restrict__ out) {
  __shared__ short As[3][8192];
  __shared__ short Bs[3][8192];
  const int brow = blockIdx.y, bcol = blockIdx.x;
  const f32x4 fz = {0.f, 0.f, 0.f, 0.f};
  f32x4 acc[4][4];
  #pragma unroll
  for (int a = 0; a < 4; ++a)
    #pragma unroll
    for (int b = 0; b < 4; ++b) acc[a][b] = fz;

  gemm_core_p3(cb + (size_t)brow * 128 * 1024, wo + (size_t)bcol * 128 * 1024,
               As, Bs, acc);

  const int tid = threadIdx.x;
  const int wv = tid >> 6, lane = tid & 63;
  const int wr = wv >> 1, wc = wv & 1;
  const int lrow = lane & 15, lk = lane >> 4;
  float bcv[4];
  #pragma unroll
  for (int nj = 0; nj < 4; ++nj)
    bcv[nj] = biaso[bcol * 128 + wc * 64 + nj * 16 + lrow];

  #pragma unroll
  for (int mi = 0; mi < 4; ++mi) {
    #pragma unroll
    for (int r = 0; r < 4; ++r) {
      const int gr = brow * 128 + wr * 64 + mi * 16 + lk * 4 + r;
      #pragma unroll
      for (int nj = 0; nj < 4; ++nj) {
        const int gc = bcol * 128 + wc * 64 + nj * 16 + lrow;
        out[(size_t)gr * 1024 + gc] = acc[mi][nj][r] + bcv[nj];
      }
    }
  }
}

// ---------------------------------------------------------------------------
extern "C" void kernel_launch(void* const* d_in, const int* in_sizes, int n_in,
                              void* d_out, int out_size, void* d_ws, size_t ws_size,
                              hipStream_t stream) {
  (void)in_sizes; (void)n_in; (void)out_size; (void)ws_size;
  const float* x   = (const float*)d_in[0];
  const float* qw  = (const float*)d_in[1];
  const float* qb  = (const float*)d_in[2];
  const float* qla = (const float*)d_in[3];
  const float* qlb = (const float*)d_in[4];
  const float* kw  = (const float*)d_in[5];
  const float* kb  = (const float*)d_in[6];
  const float* kla = (const float*)d_in[7];
  const float* klb = (const float*)d_in[8];
  const float* vw  = (const float*)d_in[9];
  const float* vb  = (const float*)d_in[10];
  const float* vla = (const float*)d_in[11];
  const float* vlb = (const float*)d_in[12];
  const float* ow  = (const float*)d_in[13];
  const float* ob  = (const float*)d_in[14];
  const float* ola = (const float*)d_in[15];
  const float* olb = (const float*)d_in[16];

  short* xb   = (short*)d_ws;                         // 4096*1024 bf16 (reused as ctx)
  short* wb   = xb + (size_t)4096 * 1024;             // 4*1024*1024 bf16
  short* qbuf = wb + (size_t)4 * 1024 * 1024;         // 64*1024*64 each
  short* kbuf = qbuf + (size_t)4194304;
  short* vtb  = kbuf + (size_t)4194304;               // total 40 MB

  prep_kernel<<<8192, 256, 0, stream>>>(x, xb, qw, kw, vw, ow,
                                        qlb, klb, vlb, olb,
                                        qla, kla, vla, ola, wb);
  gemm_qkv<<<256, 512, 0, stream>>>(xb, wb, qb, kb, vb, qbuf, kbuf, vtb);
  attn_kernel<<<dim3(64, 4), 512, 0, stream>>>(qbuf, kbuf, vtb, xb);
  gemm_o<<<dim3(8, 32), 256, 0, stream>>>(xb, wb + (size_t)3 * 1024 * 1024, ob, (float*)d_out);
}

// Round 19
// 121.461 us; speedup vs baseline: 1.0940x; 1.0021x over previous
//
#include <hip/hip_runtime.h>
#include <cstdint>

// ---------------------------------------------------------------------------
// LoRA MHA: B=4,S=1024,E=1024,H=16,D=64,R=16.  bf16 MFMA, fp32 accum.
// LoRA folded into the weights: W' = W + B@A (scale=1).
// R19: R18 base (121.71us) + gemm_o XCD remap: 1-D grid 256, xcd = wg&7
// owns 4 brows x all 8 bcols (3 MB working set fits 4 MB L2; was: each XCD
// re-reading the whole 8 MB ctx through L3).  Everything else unchanged.
// ---------------------------------------------------------------------------

typedef __attribute__((ext_vector_type(8))) short bf16x8;
typedef __attribute__((ext_vector_type(4))) float f32x4;
typedef __attribute__((ext_vector_type(16))) float f32x16;
typedef __attribute__((ext_vector_type(4))) unsigned short u16x4;
typedef __attribute__((ext_vector_type(4))) unsigned int u32x4;

__device__ __forceinline__ short f2bf(float f) {
  unsigned u = __builtin_bit_cast(unsigned, f);
  u += 0x7FFFu + ((u >> 16) & 1u);          // RNE
  return (short)(u >> 16);
}

typedef __attribute__((address_space(1))) const unsigned int as1_uint;
typedef __attribute__((address_space(3))) unsigned int as3_uint;

__device__ __forceinline__ void gload_lds16(const short* g, const short* l) {
  __builtin_amdgcn_global_load_lds((as1_uint*)g,
      (as3_uint*)(unsigned int)(uintptr_t)l, 16, 0, 0);
}

__device__ __forceinline__ unsigned cvtpk(float lo, float hi) {
  unsigned r;
  asm("v_cvt_pk_bf16_f32 %0, %1, %2" : "=v"(r) : "v"(lo), "v"(hi));
  return r;
}
__device__ __forceinline__ void plswap(unsigned &a, unsigned &b) {
  asm("v_permlane32_swap_b32 %0, %1" : "+v"(a), "+v"(b));
}

__device__ __forceinline__ void build_pfrag(const f32x16 &s, bf16x8 &f0, bf16x8 &f1) {
  unsigned x0 = cvtpk(s[0], s[1]),  x1 = cvtpk(s[2], s[3]);
  unsigned x2 = cvtpk(s[4], s[5]),  x3 = cvtpk(s[6], s[7]);
  plswap(x0, x2); plswap(x1, x3);
  unsigned y0 = cvtpk(s[8], s[9]),  y1 = cvtpk(s[10], s[11]);
  unsigned y2 = cvtpk(s[12], s[13]), y3 = cvtpk(s[14], s[15]);
  plswap(y0, y2); plswap(y1, y3);
  u32x4 a = {x0, x1, x2, x3}, b = {y0, y1, y2, y3};
  f0 = __builtin_bit_cast(bf16x8, a);
  f1 = __builtin_bit_cast(bf16x8, b);
}

// ---------------------------------------------------------------------------
// Kernel 1: fused prep.  Blocks [0,4096): cast x fp32 -> bf16 [4096][1024].
// Blocks [4096,8192): fold LoRA, W'[p] = W_p + B_p@A_p (fp32 -> bf16).
// ---------------------------------------------------------------------------
__global__ void prep_kernel(const float* __restrict__ x, short* __restrict__ xb,
                            const float* __restrict__ wq, const float* __restrict__ wk,
                            const float* __restrict__ wv, const float* __restrict__ wo,
                            const float* __restrict__ bq, const float* __restrict__ bk,
                            const float* __restrict__ bv, const float* __restrict__ bo,
                            const float* __restrict__ aq, const float* __restrict__ ak,
                            const float* __restrict__ av, const float* __restrict__ ao,
                            short* __restrict__ wbo) {
  const int b = blockIdx.x;
  if (b < 4096) {
    const int idx = b * 256 + threadIdx.x;
    f32x4 v = ((const f32x4*)x)[idx];
    u16x4 o;
    o[0] = (unsigned short)f2bf(v[0]);
    o[1] = (unsigned short)f2bf(v[1]);
    o[2] = (unsigned short)f2bf(v[2]);
    o[3] = (unsigned short)f2bf(v[3]);
    ((u16x4*)xb)[idx] = o;
  } else {
    const int bb = b - 4096;
    const int p = bb >> 10;
    const float* W  = (p == 0) ? wq : (p == 1) ? wk : (p == 2) ? wv : wo;
    const float* Bm = (p == 0) ? bq : (p == 1) ? bk : (p == 2) ? bv : bo;
    const float* A  = (p == 0) ? aq : (p == 1) ? ak : (p == 2) ? av : ao;
    const int idx = (bb & 1023) * 256 + threadIdx.x;
    const int n = idx >> 8;
    const int e4 = idx & 255;
    f32x4 acc = ((const f32x4*)(W + (size_t)n * 1024))[e4];
    const float* br = Bm + n * 16;
    #pragma unroll
    for (int r = 0; r < 16; ++r) {
      const f32x4 a4 = ((const f32x4*)(A + (size_t)r * 1024))[e4];
      const float bl = br[r];
      acc[0] += bl * a4[0];
      acc[1] += bl * a4[1];
      acc[2] += bl * a4[2];
      acc[3] += bl * a4[3];
    }
    u16x4 o;
    o[0] = (unsigned short)f2bf(acc[0]);
    o[1] = (unsigned short)f2bf(acc[1]);
    o[2] = (unsigned short)f2bf(acc[2]);
    o[3] = (unsigned short)f2bf(acc[3]);
    *(u16x4*)(wbo + (size_t)p * 1048576 + (size_t)idx * 4) = o;
  }
}

// ---------------------------------------------------------------------------
// Kernel 2: merged q/k/v projection, 256x192 tile, 8 waves (2M x 4N),
// 8-phase counted-vmcnt schedule.  Grid 256 = 16 brow x 16 bcol (100% CU
// fill), XCD swizzle (2 brows x 16 bcols per XCD).  (unchanged from R18)
// ---------------------------------------------------------------------------
__global__ __launch_bounds__(512, 1)
void gemm_qkv(const short* __restrict__ xb, const short* __restrict__ wb,
              const float* __restrict__ biasq, const float* __restrict__ biask,
              const float* __restrict__ biasv,
              short* __restrict__ qbuf, short* __restrict__ kbuf, short* __restrict__ vtb) {
  __shared__ short Ah[2][2][8192];     // [buf][half][128 rows * 64 cols]
  __shared__ short Bf[2][12288];       // [buf][192 rows * 64 cols]
  const int wg = blockIdx.x;                    // 0..255
  const int swz = (wg & 7) * 32 + (wg >> 3);    // XCD owns 2 brows x 16 bcols
  const int brow = swz >> 4, bcol = swz & 15;
  const int tid = threadIdx.x;
  const int wid = tid >> 6, lane = tid & 63;
  const int wr = wid >> 2, wc = wid & 3;        // 2M x 4N wave grid
  const int lrow = lane & 15, lk = lane >> 4;
  const int sl8 = (tid & 7) ^ ((tid >> 3) & 7); // inverse-swizzled source slot

  const short* Asrc = xb + (size_t)brow * 256 * 1024;
  const short* Bsrc = wb + (size_t)bcol * 192 * 1024;

#define STAGE_A(hf, kt, buf)                                                   \
  { _Pragma("unroll")                                                          \
    for (int i = 0; i < 2; ++i) {                                              \
      const int row = (hf) * 128 + i * 64 + (tid >> 3);                        \
      gload_lds16(Asrc + (size_t)row * 1024 + (kt) * 64 + sl8 * 8,             \
                  Ah[buf][hf] + (i * 64 + wid * 8) * 64);                      \
    } }
#define STAGE_B(ch, kt, buf)                                                   \
  {                                                                            \
    const int row = (ch) * 64 + (tid >> 3);                                    \
    gload_lds16(Bsrc + (size_t)row * 1024 + (kt) * 64 + sl8 * 8,               \
                Bf[buf] + (ch) * 4096 + tid * 8);                              \
  }

  const f32x4 fz = {0.f, 0.f, 0.f, 0.f};
  f32x4 acc[8][3];
  #pragma unroll
  for (int a = 0; a < 8; ++a)
    #pragma unroll
    for (int b = 0; b < 3; ++b) acc[a][b] = fz;

  STAGE_A(0, 0, 0)
  STAGE_A(1, 0, 0)
  STAGE_B(0, 0, 0) STAGE_B(1, 0, 0) STAGE_B(2, 0, 0)
  STAGE_B(0, 1, 1) STAGE_B(1, 1, 1) STAGE_B(2, 1, 1)
  asm volatile("s_waitcnt vmcnt(3)" ::: "memory");
  __builtin_amdgcn_s_barrier();

  for (int t = 0; t < 16; ++t) {
    const int cur = t & 1;
    bf16x8 bfr[3][2];
    #pragma unroll
    for (int q = 0; q < 4; ++q) {
      if (q == 0) {
        #pragma unroll
        for (int nj = 0; nj < 3; ++nj) {
          const int rr = wc * 48 + nj * 16 + lrow;
          #pragma unroll
          for (int kc = 0; kc < 2; ++kc)
            bfr[nj][kc] = *(const bf16x8*)(&Bf[cur][rr * 64 + (((kc * 4 + lk) ^ (rr & 7)) * 8)]);
        }
      }
      bf16x8 afr[2][2];
      #pragma unroll
      for (int m2 = 0; m2 < 2; ++m2) {
        const int rr = q * 32 + m2 * 16 + lrow;
        #pragma unroll
        for (int kc = 0; kc < 2; ++kc)
          afr[m2][kc] = *(const bf16x8*)(&Ah[cur][wr][rr * 64 + (((kc * 4 + lk) ^ (rr & 7)) * 8)]);
      }
      if (q == 0)      { if (t + 1 < 16) STAGE_A(0, t + 1, cur ^ 1) }
      else if (q == 1) { if (t + 1 < 16) STAGE_A(1, t + 1, cur ^ 1) }
      else if (q == 2) { if (t + 2 < 16) { STAGE_B(0, t + 2, cur) STAGE_B(1, t + 2, cur) } }
      else             { if (t + 2 < 16) STAGE_B(2, t + 2, cur) }

      if (q == 0) asm volatile("s_waitcnt lgkmcnt(6)" ::: "memory");
      __builtin_amdgcn_s_barrier();
      asm volatile("s_waitcnt lgkmcnt(0)" ::: "memory");
      __builtin_amdgcn_s_setprio(1);
      #pragma unroll
      for (int kc = 0; kc < 2; ++kc)
        #pragma unroll
        for (int m2 = 0; m2 < 2; ++m2)
          #pragma unroll
          for (int nj = 0; nj < 3; ++nj)
            acc[q * 2 + m2][nj] = __builtin_amdgcn_mfma_f32_16x16x32_bf16(
                afr[m2][kc], bfr[nj][kc], acc[q * 2 + m2][nj], 0, 0, 0);
      __builtin_amdgcn_s_setprio(0);
      if (q == 3) {
        if (t < 14) asm volatile("s_waitcnt vmcnt(3)" ::: "memory");
        else        asm volatile("s_waitcnt vmcnt(0)" ::: "memory");
      }
      __builtin_amdgcn_s_barrier();
    }
  }
#undef STAGE_A
#undef STAGE_B

  const float SCALE = 0.18033688f;   // log2(e)/8 folded into q
  #pragma unroll
  for (int mi = 0; mi < 8; ++mi) {
    #pragma unroll
    for (int r = 0; r < 4; ++r) {
      const int gr = brow * 256 + wr * 128 + mi * 16 + lk * 4 + r;   // C/D row
      const int bb = gr >> 10, s = gr & 1023;
      #pragma unroll
      for (int nj = 0; nj < 3; ++nj) {
        const int gc = bcol * 192 + wc * 48 + nj * 16 + lrow;        // 0..3071
        const int p = gc >> 10, pc = gc & 1023;
        const float bv = ((p == 0) ? biasq : (p == 1) ? biask : biasv)[pc];
        const float v = (acc[mi][nj][r] + bv) * ((p == 0) ? SCALE : 1.0f);
        const int h = pc >> 6, d = pc & 63;
        const int bh = bb * 16 + h;
        if (p == 2)
          vtb[((size_t)bh * 64 + d) * 1024 + s] = f2bf(v);
        else
          ((p == 0) ? qbuf : kbuf)[((size_t)bh * 1024 + s) * 64 + d] = f2bf(v);
      }
    }
  }
}

// ---------------------------------------------------------------------------
// Kernel 3: flash attention, swapped 32x32 MFMA form (unchanged from R18).
// 8-wave blocks (512 thr, 256 q-rows), grid (64 bh, 4 qt) = 256 blocks.
// 3-buffer LDS ring + counted vmcnt (T4).
// ---------------------------------------------------------------------------
__global__ __launch_bounds__(512)
void attn_kernel(const short* __restrict__ qbuf, const short* __restrict__ kbuf,
                 const short* __restrict__ vtb, short* __restrict__ cb) {
  __shared__ short Ks[3][64 * 64];
  __shared__ short Vs[3][64 * 64];
  const int bh = blockIdx.x, qt = blockIdx.y;
  const int tid = threadIdx.x, w = tid >> 6, lane = tid & 63;
  const int l31 = lane & 31, hi = lane >> 5;
  const int srow = lane >> 3, sphys = lane & 7;
  const short* Qp = qbuf + (size_t)bh * 65536;
  const short* Kp = kbuf + (size_t)bh * 65536;
  const short* Vp = vtb + (size_t)bh * 65536;
  const int q0 = qt * 256 + w * 32;

  bf16x8 bq[4];
  #pragma unroll
  for (int kc = 0; kc < 4; ++kc)
    bq[kc] = *(const bf16x8*)(Qp + (size_t)(q0 + l31) * 64 + kc * 16 + hi * 8);

  const f32x16 fz16 = {0.f,0.f,0.f,0.f,0.f,0.f,0.f,0.f,0.f,0.f,0.f,0.f,0.f,0.f,0.f,0.f};
  float m_run = -1e30f, l_run = 0.f;
  f32x16 acc0 = fz16, acc1 = fz16;

  #define STAGE_KV(buf, tt)                                                  \
    {                                                                        \
      const int t0s = (tt) * 64;                                             \
      const int row = w * 8 + srow;                                          \
      const int sl = sphys ^ (row & 7);                                      \
      gload_lds16(Kp + (size_t)(t0s + row) * 64 + sl * 8, Ks[buf] + w * 512); \
      gload_lds16(Vp + (size_t)row * 1024 + t0s + sl * 8, Vs[buf] + w * 512); \
    }

  STAGE_KV(0, 0);

  int cur = 0, nxt = 1;
  for (int tt = 0; tt < 16; ++tt) {
    if (tt < 15) {
      STAGE_KV(nxt, tt + 1);
      asm volatile("s_waitcnt vmcnt(2)" ::: "memory");   // tile tt landed (mine)
    } else {
      asm volatile("s_waitcnt vmcnt(0)" ::: "memory");
    }
    asm volatile("s_waitcnt lgkmcnt(0)" ::: "memory");   // my prev reads retired
    __builtin_amdgcn_s_barrier();                        // all waves: tile tt ready

    // ---- S^T = K · Q^T ----
    f32x16 s0 = fz16, s1 = fz16;
    __builtin_amdgcn_s_setprio(1);
    #pragma unroll
    for (int kc = 0; kc < 4; ++kc) {
      const int slot = (kc * 2 + hi) ^ (l31 & 7);
      const bf16x8 ak0 = *(const bf16x8*)(Ks[cur] + l31 * 64 + slot * 8);
      const bf16x8 ak1 = *(const bf16x8*)(Ks[cur] + (32 + l31) * 64 + slot * 8);
      s0 = __builtin_amdgcn_mfma_f32_32x32x16_bf16(ak0, bq[kc], s0, 0, 0, 0);
      s1 = __builtin_amdgcn_mfma_f32_32x32x16_bf16(ak1, bq[kc], s1, 0, 0, 0);
    }
    __builtin_amdgcn_s_setprio(0);

    // ---- max: pairwise tree ----
    float t16[16];
    #pragma unroll
    for (int r = 0; r < 8; ++r) t16[r] = fmaxf(s0[2 * r], s0[2 * r + 1]);
    #pragma unroll
    for (int r = 0; r < 8; ++r) t16[8 + r] = fmaxf(s1[2 * r], s1[2 * r + 1]);
    #pragma unroll
    for (int r = 0; r < 8; ++r) t16[r] = fmaxf(t16[r], t16[r + 8]);
    #pragma unroll
    for (int r = 0; r < 4; ++r) t16[r] = fmaxf(t16[r], t16[r + 4]);
    float tm = fmaxf(fmaxf(t16[0], t16[1]), fmaxf(t16[2], t16[3]));
    tm = fmaxf(tm, __shfl_xor(tm, 32, 64));

    // ---- defer-max (T13) ----
    if (__any(tm - m_run > 8.0f)) {
      const float mn = fmaxf(m_run, tm);
      const float alpha = exp2f(m_run - mn);
      m_run = mn;
      l_run *= alpha;
      #pragma unroll
      for (int r = 0; r < 16; ++r) { acc0[r] *= alpha; acc1[r] *= alpha; }
    }

    // ---- P = 2^(S - m), sum via pairwise tree ----
    float a16[16];
    #pragma unroll
    for (int r = 0; r < 16; ++r) { s0[r] = exp2f(s0[r] - m_run); }
    #pragma unroll
    for (int r = 0; r < 16; ++r) { s1[r] = exp2f(s1[r] - m_run); }
    #pragma unroll
    for (int r = 0; r < 8; ++r) a16[r] = s0[2 * r] + s0[2 * r + 1];
    #pragma unroll
    for (int r = 0; r < 8; ++r) a16[8 + r] = s1[2 * r] + s1[2 * r + 1];
    #pragma unroll
    for (int r = 0; r < 8; ++r) a16[r] += a16[r + 8];
    #pragma unroll
    for (int r = 0; r < 4; ++r) a16[r] += a16[r + 4];
    float rs = (a16[0] + a16[1]) + (a16[2] + a16[3]);
    rs += __shfl_xor(rs, 32, 64);
    l_run += rs;

    // ---- P^T fragments (in-register, T12) ----
    bf16x8 pf[4];
    build_pfrag(s0, pf[0], pf[1]);
    build_pfrag(s1, pf[2], pf[3]);

    // ---- O^T += V^T · P^T ----
    __builtin_amdgcn_s_setprio(1);
    #pragma unroll
    for (int kc4 = 0; kc4 < 4; ++kc4) {
      const int slot = (kc4 * 2 + hi) ^ (l31 & 7);
      const bf16x8 av0 = *(const bf16x8*)(Vs[cur] + l31 * 64 + slot * 8);
      const bf16x8 av1 = *(const bf16x8*)(Vs[cur] + (32 + l31) * 64 + slot * 8);
      acc0 = __builtin_amdgcn_mfma_f32_32x32x16_bf16(av0, pf[kc4], acc0, 0, 0, 0);
      acc1 = __builtin_amdgcn_mfma_f32_32x32x16_bf16(av1, pf[kc4], acc1, 0, 0, 0);
    }
    __builtin_amdgcn_s_setprio(0);

    cur = (cur == 2) ? 0 : (cur + 1);
    nxt = (nxt == 2) ? 0 : (nxt + 1);
  }

  const int bb = bh >> 4, h = bh & 15;
  const int s = q0 + l31;
  short* crow = cb + (size_t)(bb * 1024 + s) * 1024 + h * 64;
  const float inv = 1.f / l_run;
  #pragma unroll
  for (int rp = 0; rp < 8; ++rp) {
    const int r = rp * 2;
    const int d = (r & 3) + 8 * (r >> 2) + 4 * hi;
    const unsigned p0 = (unsigned)(unsigned short)f2bf(acc0[r] * inv)
                      | ((unsigned)(unsigned short)f2bf(acc0[r + 1] * inv) << 16);
    const unsigned p1 = (unsigned)(unsigned short)f2bf(acc1[r] * inv)
                      | ((unsigned)(unsigned short)f2bf(acc1[r + 1] * inv) << 16);
    *(unsigned*)(crow + d) = p0;
    *(unsigned*)(crow + 32 + d) = p1;
  }
  #undef STAGE_KV
}

// ---------------------------------------------------------------------------
// GEMM core, depth-2 counted-vmcnt pipeline (gemm_o).
// ---------------------------------------------------------------------------
__device__ __forceinline__ void gemm_core_p3(const short* __restrict__ xrow,
                                             const short* __restrict__ wrow,
                                             short (&As)[3][8192], short (&Bs)[3][8192],
                                             f32x4 (&acc)[4][4]) {
  const int tid = threadIdx.x;
  const int wv = tid >> 6, lane = tid & 63;
  const int wr = wv >> 1, wc = wv & 1;
  const int lrow = lane & 15, lk = lane >> 4;
  const int srow = lane >> 3, sphys = lane & 7;

#define STAGE_G(buf, kt)                                                       \
  {                                                                            \
    _Pragma("unroll")                                                          \
    for (int i = 0; i < 4; ++i) {                                              \
      const int ch = i * 4 + wv;                                               \
      const int row = ch * 8 + srow;                                           \
      const int sl = sphys ^ (row & 7);                                        \
      gload_lds16(xrow + (size_t)row * 1024 + (kt) * 64 + sl * 8, As[buf] + ch * 512); \
      gload_lds16(wrow + (size_t)row * 1024 + (kt) * 64 + sl * 8, Bs[buf] + ch * 512); \
    }                                                                          \
  }

  STAGE_G(0, 0);
  STAGE_G(1, 1);
  int cur = 0;
  for (int kt = 0; kt < 16; ++kt) {
    if (kt < 14) {
      const int nb = (cur == 0) ? 2 : (cur - 1);   // (kt+2)%3
      STAGE_G(nb, kt + 2);
      asm volatile("s_waitcnt vmcnt(16)" ::: "memory");
    } else if (kt == 14) {
      asm volatile("s_waitcnt vmcnt(8)" ::: "memory");
    } else {
      asm volatile("s_waitcnt vmcnt(0)" ::: "memory");
    }
    __builtin_amdgcn_s_barrier();

    #pragma unroll
    for (int kc = 0; kc < 2; ++kc) {
      bf16x8 af[4], bw[4];
      #pragma unroll
      for (int mi = 0; mi < 4; ++mi) {
        const int row = wr * 64 + mi * 16 + lrow;
        const int slot = (kc * 4 + lk) ^ (row & 7);
        af[mi] = *(const bf16x8*)(As[cur] + row * 64 + slot * 8);
      }
      #pragma unroll
      for (int nj = 0; nj < 4; ++nj) {
        const int row = wc * 64 + nj * 16 + lrow;
        const int slot = (kc * 4 + lk) ^ (row & 7);
        bw[nj] = *(const bf16x8*)(Bs[cur] + row * 64 + slot * 8);
      }
      __builtin_amdgcn_s_setprio(1);
      #pragma unroll
      for (int mi = 0; mi < 4; ++mi)
        #pragma unroll
        for (int nj = 0; nj < 4; ++nj)
          acc[mi][nj] = __builtin_amdgcn_mfma_f32_16x16x32_bf16(af[mi], bw[nj], acc[mi][nj], 0, 0, 0);
      __builtin_amdgcn_s_setprio(0);
    }

    asm volatile("s_waitcnt lgkmcnt(0)" ::: "memory");
    __builtin_amdgcn_s_barrier();
    cur = (cur == 2) ? 0 : (cur + 1);
  }
#undef STAGE_G
}

// ---------------------------------------------------------------------------
// Kernel 4: o-projection -> fp32 d_out (p3 core).  1-D grid 256; XCD remap:
// xcd = wg&7 owns brows [4*xcd, 4*xcd+4) x all 8 bcols (A 1 MB + wo 2 MB
// working set fits the 4 MB L2).
// ---------------------------------------------------------------------------
__global__ __launch_bounds__(256)
void gemm_o(const short* __restrict__ cb, const short* __restrict__ wo,
            const float* __restrict__ biaso, float* __restrict__ out) {
  __shared__ short As[3][8192];
  __shared__ short Bs[3][8192];
  const int wg = blockIdx.x;              // 0..255
  const int xcd = wg & 7, ix = wg >> 3;   // 32 blocks per XCD
  const int brow = xcd * 4 + (ix & 3);    // 4 brows per XCD
  const int bcol = ix >> 2;               // all 8 bcols
  const f32x4 fz = {0.f, 0.f, 0.f, 0.f};
  f32x4 acc[4][4];
  #pragma unroll
  for (int a = 0; a < 4; ++a)
    #pragma unroll
    for (int b = 0; b < 4; ++b) acc[a][b] = fz;

  gemm_core_p3(cb + (size_t)brow * 128 * 1024, wo + (size_t)bcol * 128 * 1024,
               As, Bs, acc);

  const int tid = threadIdx.x;
  const int wv = tid >> 6, lane = tid & 63;
  const int wr = wv >> 1, wc = wv & 1;
  const int lrow = lane & 15, lk = lane >> 4;
  float bcv[4];
  #pragma unroll
  for (int nj = 0; nj < 4; ++nj)
    bcv[nj] = biaso[bcol * 128 + wc * 64 + nj * 16 + lrow];

  #pragma unroll
  for (int mi = 0; mi < 4; ++mi) {
    #pragma unroll
    for (int r = 0; r < 4; ++r) {
      const int gr = brow * 128 + wr * 64 + mi * 16 + lk * 4 + r;
      #pragma unroll
      for (int nj = 0; nj < 4; ++nj) {
        const int gc = bcol * 128 + wc * 64 + nj * 16 + lrow;
        out[(size_t)gr * 1024 + gc] = acc[mi][nj][r] + bcv[nj];
      }
    }
  }
}

// ---------------------------------------------------------------------------
extern "C" void kernel_launch(void* const* d_in, const int* in_sizes, int n_in,
                              void* d_out, int out_size, void* d_ws, size_t ws_size,
                              hipStream_t stream) {
  (void)in_sizes; (void)n_in; (void)out_size; (void)ws_size;
  const float* x   = (const float*)d_in[0];
  const float* qw  = (const float*)d_in[1];
  const float* qb  = (const float*)d_in[2];
  const float* qla = (const float*)d_in[3];
  const float* qlb = (const float*)d_in[4];
  const float* kw  = (const float*)d_in[5];
  const float* kb  = (const float*)d_in[6];
  const float* kla = (const float*)d_in[7];
  const float* klb = (const float*)d_in[8];
  const float* vw  = (const float*)d_in[9];
  const float* vb  = (const float*)d_in[10];
  const float* vla = (const float*)d_in[11];
  const float* vlb = (const float*)d_in[12];
  const float* ow  = (const float*)d_in[13];
  const float* ob  = (const float*)d_in[14];
  const float* ola = (const float*)d_in[15];
  const float* olb = (const float*)d_in[16];

  short* xb   = (short*)d_ws;                         // 4096*1024 bf16 (reused as ctx)
  short* wb   = xb + (size_t)4096 * 1024;             // 4*1024*1024 bf16
  short* qbuf = wb + (size_t)4 * 1024 * 1024;         // 64*1024*64 each
  short* kbuf = qbuf + (size_t)4194304;
  short* vtb  = kbuf + (size_t)4194304;               // total 40 MB

  prep_kernel<<<8192, 256, 0, stream>>>(x, xb, qw, kw, vw, ow,
                                        qlb, klb, vlb, olb,
                                        qla, kla, vla, ola, wb);
  gemm_qkv<<<256, 512, 0, stream>>>(xb, wb, qb, kb, vb, qbuf, kbuf, vtb);
  attn_kernel<<<dim3(64, 4), 512, 0, stream>>>(qbuf, kbuf, vtb, xb);
  gemm_o<<<256, 256, 0, stream>>>(xb, wb + (size_t)3 * 1024 * 1024, ob, (float*)d_out);
}